// Round 9
// baseline (1652.062 us; speedup 1.0000x reference)
//
#include <hip/hip_runtime.h>
#include <hip/hip_cooperative_groups.h>
#include <math.h>

namespace cg = cooperative_groups;

#define D 128
#define LOG2E 1.44269504f
#define LAYER_GRID 1024
#define GPB 4                      // node-groups per block in k_layer

typedef short bf16x8 __attribute__((ext_vector_type(8)));
typedef float f32x4 __attribute__((ext_vector_type(4)));
typedef float f4 __attribute__((ext_vector_type(4)));
typedef unsigned short u16x4 __attribute__((ext_vector_type(4)));

__device__ __forceinline__ unsigned short f2bf(float f) {
    unsigned int u = __float_as_uint(f);
    u += 0x7fff + ((u >> 16) & 1);   // round-to-nearest-even
    return (unsigned short)(u >> 16);
}
__device__ __forceinline__ float bf2f(unsigned short h) {
    return __uint_as_float(((unsigned int)h) << 16);
}
__device__ __forceinline__ bf16x8 load_bf8(const unsigned short* p) {
    return __builtin_bit_cast(bf16x8, *reinterpret_cast<const uint4*>(p));
}
// raw HW transcendentals (v_exp_f32 = 2^x, v_log_f32 = log2)
__device__ __forceinline__ float exp2_hw(float x) {
    float r; asm("v_exp_f32 %0, %1" : "=v"(r) : "v"(x)); return r;
}
__device__ __forceinline__ float log2_hw(float x) {
    float r; asm("v_log_f32 %0, %1" : "=v"(r) : "v"(x)); return r;
}

// x[n][d] = emb[z[n]][d]; also emit bf16 hi/lo split. float4 per thread.
__global__ __launch_bounds__(256) void k_embed(const int* __restrict__ z,
        const float* __restrict__ emb, float* __restrict__ x,
        unsigned short* __restrict__ xh, unsigned short* __restrict__ xl, int N) {
    int idx = blockIdx.x * blockDim.x + threadIdx.x;       // N*32 threads
    if (idx >= N * 32) return;
    int n = idx >> 5;
    int d0 = (idx & 31) * 4;
    f4 v = *reinterpret_cast<const f4*>(emb + (size_t)z[n] * D + d0);
    *reinterpret_cast<f4*>(x + (size_t)n * D + d0) = v;
    u16x4 h, l;
    #pragma unroll
    for (int c = 0; c < 4; c++) {
        h[c] = f2bf(v[c]);
        l[c] = f2bf(v[c] - bf2f(h[c]));
    }
    *reinterpret_cast<u16x4*>(xh + (size_t)n * D + d0) = h;
    *reinterpret_cast<u16x4*>(xl + (size_t)n * D + d0) = l;
}

// jd[e] = (row[e], bits(||pos[row]-pos[col]||)) packed
__global__ void k_dist(const int* __restrict__ row, const int* __restrict__ col,
                       const float* __restrict__ pos, int2* __restrict__ jd, int E) {
    int e = blockIdx.x * blockDim.x + threadIdx.x;
    if (e >= E) return;
    int r = row[e], c = col[e];
    float dx = pos[3 * r + 0] - pos[3 * c + 0];
    float dy = pos[3 * r + 1] - pos[3 * c + 1];
    float dz = pos[3 * r + 2] - pos[3 * c + 2];
    float dist = sqrtf(dx * dx + dy * dy + dz * dz);
    jd[e] = make_int2(r, __float_as_int(dist));
}

// Pre-transpose + bf16 hi/lo split all layer weights, PRE-SCALED for base-2 gate:
// f-path (mats 0,1) x (-log2e), s-path (mats 2,3) x (+log2e).
__global__ void k_cvtW(const float* __restrict__ Wf, const float* __restrict__ Ws,
                       unsigned short* __restrict__ Wth, unsigned short* __restrict__ Wtl,
                       int L) {
    int idx = blockIdx.x * blockDim.x + threadIdx.x;
    if (idx >= L * 4 * D * D) return;
    int k = idx & 127;
    int n = (idx >> 7) & 127;
    int mat = (idx >> 14) & 3;
    int l = idx >> 16;
    const float* src = (mat < 2) ? Wf : Ws;
    float scale = (mat < 2) ? -LOG2E : LOG2E;
    float v = scale * src[(size_t)l * 257 * D + (size_t)((mat & 1) * D + k) * D + n];
    unsigned short h = f2bf(v);
    Wth[idx] = h;
    Wtl[idx] = f2bf(v - bf2f(h));
}

// Split-bf16 MFMA GEMM (2-term: Xh*Wh + Xl*Wh), graph-affine XCD swizzle.
// Outputs interleaved: AfAs[N][256] = [Af|As], BfBs[N][256] = [Bf|Bs]  (pre-scaled)
__global__ __launch_bounds__(256) void k_gemm_mfma(
        const unsigned short* __restrict__ Xh, const unsigned short* __restrict__ Xl,
        const unsigned short* __restrict__ Wth, const unsigned short* __restrict__ Wtl,
        const float* __restrict__ bfl, const float* __restrict__ bsl,
        float* __restrict__ AfAs, float* __restrict__ BfBs, int S, int G) {
    int mat = blockIdx.y;                      // 0=Af 1=Bf 2=As 3=Bs
    float* O = ((mat & 1) ? BfBs : AfAs) + ((mat >> 1) ? 128 : 0);
    const float* bias = (mat == 0) ? bfl : (mat == 2) ? bsl : nullptr;
    float bsc = (mat == 0) ? -LOG2E : LOG2E;
    const unsigned short* Wh = Wth + (size_t)mat * D * D;

    int wave = threadIdx.x >> 6;
    int lane = threadIdx.x & 63;
    int r16 = lane & 15;
    int kg = lane >> 4;

    int xb = blockIdx.x;
    int tile0;
    if ((G & 7) == 0 && (S & 127) == 0) {
        int xcd = xb & 7, i = xb >> 3;
        int tpg = S >> 7;                       // 128-row tiles per graph
        int gi = i / tpg, t = i - gi * tpg;
        tile0 = (xcd + 8 * gi) * S + t * 128;   // graph g on XCD g%8
    } else tile0 = xb * 128;
    int row0 = tile0 + (wave >> 1) * 64;
    int wc = (wave & 1) * 64;

    f32x4 acc[4][4];
    #pragma unroll
    for (int m = 0; m < 4; m++)
        #pragma unroll
        for (int n = 0; n < 4; n++) acc[m][n] = (f32x4){0.f, 0.f, 0.f, 0.f};

    #pragma unroll
    for (int ks = 0; ks < 4; ++ks) {
        int k0 = ks * 32 + kg * 8;
        bf16x8 ah[4], al[4], bh[4];
        #pragma unroll
        for (int m = 0; m < 4; m++) {
            size_t off = (size_t)(row0 + m * 16 + r16) * D + k0;
            ah[m] = load_bf8(Xh + off);
            al[m] = load_bf8(Xl + off);
        }
        #pragma unroll
        for (int n = 0; n < 4; n++) {
            size_t off = (size_t)(wc + n * 16 + r16) * D + k0;
            bh[n] = load_bf8(Wh + off);
        }
        #pragma unroll
        for (int m = 0; m < 4; m++)
            #pragma unroll
            for (int n = 0; n < 4; n++) {
                acc[m][n] = __builtin_amdgcn_mfma_f32_16x16x32_bf16(ah[m], bh[n], acc[m][n], 0, 0, 0);
                acc[m][n] = __builtin_amdgcn_mfma_f32_16x16x32_bf16(al[m], bh[n], acc[m][n], 0, 0, 0);
            }
    }

    // C/D layout: col = lane&15, row = (lane>>4)*4 + reg
    #pragma unroll
    for (int n = 0; n < 4; n++) {
        int col = wc + n * 16 + r16;
        float bv = bias ? bias[col] * bsc : 0.0f;
        #pragma unroll
        for (int m = 0; m < 4; m++) {
            int rbase = row0 + m * 16 + kg * 4;
            #pragma unroll
            for (int r = 0; r < 4; r++)
                O[(size_t)(rbase + r) * 256 + col] = acc[m][n][r] + bv;
        }
    }
}

__device__ __forceinline__ int swz_node0(int gi, int S, int G) {
    if ((G & 7) == 0 && (S & 7) == 0) {
        int xcd = gi & 7, i = gi >> 3;
        int bpg = S >> 3;
        int gr = i / bpg, li = i - gr * bpg;
        return (xcd + 8 * gr) * S + li * 8;     // graph g on XCD g%8
    }
    return gi * 8;
}

// ============ cooperative fused layer ============
// edges+stats1 -> grid.sync -> BN1+res (xn in regs)+stats2 -> grid.sync -> BN2+ReLU
// 1024 blocks x 256 thr, 4 blocks/CU guaranteed by __launch_bounds__(256,4).
// st layout: [0..2047] st1 8x(sum128|sq128); [2048..4095] st2 same.
__global__ __launch_bounds__(256, 4) void k_layer(
        const int2* __restrict__ jd,
        const float* __restrict__ AfAs, const float* __restrict__ BfBs,
        const float* __restrict__ wfd, const float* __restrict__ wsd,
        const float* __restrict__ gc, const float* __restrict__ bc,
        const float* __restrict__ gn, const float* __restrict__ bnb,
        float* __restrict__ x, unsigned short* __restrict__ xh,
        unsigned short* __restrict__ xl, float* __restrict__ st,
        int N, int S, int G, int deg) {
    __shared__ int2 jds[512];
    __shared__ f4 sred[256];
    __shared__ f4 sredq[256];
    cg::grid_group gg = cg::this_grid();
    int b = blockIdx.x;
    int tid = threadIdx.x;
    int grp = tid >> 5, lane = tid & 31;
    int d0 = lane * 4;
    int NG = (N + 7) >> 3;
    bool use_lds = (8 * deg) <= 512;

    const f4 wf4 = *reinterpret_cast<const f4*>(wfd + d0) * (-LOG2E);
    const f4 ws4 = *reinterpret_cast<const f4*>(wsd + d0) * (LOG2E);

    int nodes[GPB];
    f4 accs[GPB];
    #pragma unroll
    for (int s = 0; s < GPB; s++) { nodes[s] = -1; accs[s] = (f4){0.f, 0.f, 0.f, 0.f}; }

    // ---- phase 1: edge gate + aggregate over GPB node-groups ----
    #pragma unroll
    for (int s = 0; s < GPB; s++) {
        int gi = b + s * LAYER_GRID;
        if (gi < NG) {
            int node0 = swz_node0(gi, S, G);
            __syncthreads();                        // jds reuse guard
            if (use_lds) {
                int tot = 8 * deg;
                int lim = (node0 + 8 <= N) ? tot : (N > node0 ? (N - node0) * deg : 0);
                for (int t = tid; t < lim; t += 256) jds[t] = jd[(size_t)node0 * deg + t];
            }
            __syncthreads();
            int node = node0 + grp;
            if (node < N) {
                nodes[s] = node;
                const f4 af4 = *reinterpret_cast<const f4*>(AfAs + (size_t)node * 256 + d0);
                const f4 as4 = *reinterpret_cast<const f4*>(AfAs + (size_t)node * 256 + 128 + d0);
                const int2* jrow = use_lds ? (jds + grp * deg) : (jd + (size_t)node * deg);
                f4 a = {0.f, 0.f, 0.f, 0.f};
                #pragma unroll 8
                for (int e = 0; e < deg; e++) {
                    int2 p = jrow[e];
                    float dst = __int_as_float(p.y);
                    int off = (p.x << 8) + d0;
                    f4 bf4 = *reinterpret_cast<const f4*>(BfBs + off);
                    f4 bs4 = *reinterpret_cast<const f4*>(BfBs + off + 128);
                    #pragma unroll
                    for (int c = 0; c < 4; c++) {
                        float u2 = fmaf(dst, wf4[c], af4[c]) + bf4[c];   // -log2e*u
                        float v2 = fmaf(dst, ws4[c], as4[c]) + bs4[c];   // +log2e*v
                        float sE = exp2_hw(u2);
                        float tE = exp2_hw(v2);
                        float sg = __builtin_amdgcn_rcpf(1.0f + sE);
                        float sp = log2_hw(1.0f + tE);
                        a[c] = fmaf(sg, sp, a[c]);
                    }
                }
                accs[s] = a;
            }
        }
    }
    // stats1
    f4 ssum = {0.f, 0.f, 0.f, 0.f}, ssq = {0.f, 0.f, 0.f, 0.f};
    #pragma unroll
    for (int s = 0; s < GPB; s++) { ssum += accs[s]; ssq += accs[s] * accs[s]; }
    __syncthreads();
    sred[tid] = ssum;
    sredq[tid] = ssq;
    __syncthreads();
    if (tid < 64) {
        int which = tid >> 5, l = tid & 31;
        f4 sacc = which ? sredq[l] : sred[l];
        #pragma unroll
        for (int q = 1; q < 8; q++) sacc += which ? sredq[q * 32 + l] : sred[q * 32 + l];
        float* dstp = st + (b & 7) * 256 + which * 128;
        #pragma unroll
        for (int c = 0; c < 4; c++) atomicAdd(dstp + l * 4 + c, sacc[c]);
    }
    gg.sync();

    // ---- phase 2: BN1 + residual (xn in regs) + stats2 ----
    float invN = 1.0f / (float)N;
    f4 mu1 = {0.f, 0.f, 0.f, 0.f}, sq1 = {0.f, 0.f, 0.f, 0.f};
    #pragma unroll
    for (int r = 0; r < 8; r++) {
        mu1 += *reinterpret_cast<const f4*>(st + r * 256 + d0);
        sq1 += *reinterpret_cast<const f4*>(st + r * 256 + 128 + d0);
    }
    f4 g1 = *reinterpret_cast<const f4*>(gc + d0);
    f4 b1v = *reinterpret_cast<const f4*>(bc + d0);
    f4 inv1;
    #pragma unroll
    for (int c = 0; c < 4; c++) {
        float m = mu1[c] * invN;
        mu1[c] = m;
        inv1[c] = rsqrtf(sq1[c] * invN - m * m + 1e-5f);
    }
    f4 xns[GPB];
    f4 sa = {0.f, 0.f, 0.f, 0.f}, sb = {0.f, 0.f, 0.f, 0.f};
    #pragma unroll
    for (int s = 0; s < GPB; s++) {
        xns[s] = (f4){0.f, 0.f, 0.f, 0.f};
        if (nodes[s] >= 0) {
            f4 xv = *reinterpret_cast<const f4*>(x + (size_t)nodes[s] * D + d0);
            f4 xn;
            #pragma unroll
            for (int c = 0; c < 4; c++)
                xn[c] = fmaf(g1[c] * (accs[s][c] - mu1[c]), inv1[c], b1v[c]) + xv[c];
            xns[s] = xn;
            sa += xn;
            sb += xn * xn;
        }
    }
    __syncthreads();                                // sred reuse guard
    sred[tid] = sa;
    sredq[tid] = sb;
    __syncthreads();
    if (tid < 64) {
        int which = tid >> 5, l = tid & 31;
        f4 sacc = which ? sredq[l] : sred[l];
        #pragma unroll
        for (int q = 1; q < 8; q++) sacc += which ? sredq[q * 32 + l] : sred[q * 32 + l];
        float* dstp = st + 2048 + (b & 7) * 256 + which * 128;
        #pragma unroll
        for (int c = 0; c < 4; c++) atomicAdd(dstp + l * 4 + c, sacc[c]);
    }
    gg.sync();

    // ---- phase 3: BN2 + ReLU -> x, xh, xl ----
    f4 mu2 = {0.f, 0.f, 0.f, 0.f}, sq2 = {0.f, 0.f, 0.f, 0.f};
    #pragma unroll
    for (int r = 0; r < 8; r++) {
        mu2 += *reinterpret_cast<const f4*>(st + 2048 + r * 256 + d0);
        sq2 += *reinterpret_cast<const f4*>(st + 2048 + r * 256 + 128 + d0);
    }
    f4 g2 = *reinterpret_cast<const f4*>(gn + d0);
    f4 b2v = *reinterpret_cast<const f4*>(bnb + d0);
    f4 inv2;
    #pragma unroll
    for (int c = 0; c < 4; c++) {
        float m = mu2[c] * invN;
        mu2[c] = m;
        inv2[c] = rsqrtf(sq2[c] * invN - m * m + 1e-5f);
    }
    #pragma unroll
    for (int s = 0; s < GPB; s++) {
        if (nodes[s] < 0) continue;
        f4 o;
        u16x4 h, l;
        #pragma unroll
        for (int c = 0; c < 4; c++) {
            float t = fmaf(g2[c] * (xns[s][c] - mu2[c]), inv2[c], b2v[c]);
            t = fmaxf(t, 0.0f);
            o[c] = t;
            h[c] = f2bf(t);
            l[c] = f2bf(t - bf2f(h[c]));
        }
        *reinterpret_cast<f4*>(x + (size_t)nodes[s] * D + d0) = o;
        *reinterpret_cast<u16x4*>(xh + (size_t)nodes[s] * D + d0) = h;
        *reinterpret_cast<u16x4*>(xl + (size_t)nodes[s] * D + d0) = l;
    }
}

// ============ fallback path (proven R6 kernels) ============
__global__ __launch_bounds__(256) void k_edges(
        const int2* __restrict__ jd,
        const float* __restrict__ AfAs, const float* __restrict__ BfBs,
        const float* __restrict__ wfd, const float* __restrict__ wsd,
        float* __restrict__ agg, float* __restrict__ st1, int N, int S, int G, int deg) {
    __shared__ int2 jds[512];
    __shared__ f4 sred[256];
    __shared__ f4 sredq[256];
    int b = blockIdx.x;
    int node0 = swz_node0(b, S, G);
    int tid = threadIdx.x;
    int grp = tid >> 5, lane = tid & 31;
    bool use_lds = (8 * deg) <= 512;
    if (use_lds) {
        int tot = 8 * deg;
        int lim = (node0 + 8 <= N) ? tot : (N > node0 ? (N - node0) * deg : 0);
        for (int t = tid; t < lim; t += 256) jds[t] = jd[(size_t)node0 * deg + t];
    }
    __syncthreads();
    int node = node0 + grp;
    bool active = node < N;
    int d0 = lane * 4;
    f4 acc = {0.f, 0.f, 0.f, 0.f};
    if (active) {
        const f4 af4 = *reinterpret_cast<const f4*>(AfAs + (size_t)node * 256 + d0);
        const f4 as4 = *reinterpret_cast<const f4*>(AfAs + (size_t)node * 256 + 128 + d0);
        const f4 wf4 = *reinterpret_cast<const f4*>(wfd + d0) * (-LOG2E);
        const f4 ws4 = *reinterpret_cast<const f4*>(wsd + d0) * (LOG2E);
        const int2* jrow = use_lds ? (jds + grp * deg) : (jd + (size_t)node * deg);
        #pragma unroll 8
        for (int e = 0; e < deg; e++) {
            int2 p = jrow[e];
            float dst = __int_as_float(p.y);
            int off = (p.x << 8) + d0;
            f4 bf4 = *reinterpret_cast<const f4*>(BfBs + off);
            f4 bs4 = *reinterpret_cast<const f4*>(BfBs + off + 128);
            #pragma unroll
            for (int c = 0; c < 4; c++) {
                float u2 = fmaf(dst, wf4[c], af4[c]) + bf4[c];
                float v2 = fmaf(dst, ws4[c], as4[c]) + bs4[c];
                float sE = exp2_hw(u2);
                float tE = exp2_hw(v2);
                float sg = __builtin_amdgcn_rcpf(1.0f + sE);
                float sp = log2_hw(1.0f + tE);
                acc[c] = fmaf(sg, sp, acc[c]);
            }
        }
        *reinterpret_cast<f4*>(agg + (size_t)node * D + d0) = acc;
    }
    sred[tid] = acc;
    sredq[tid] = acc * acc;
    __syncthreads();
    if (tid < 64) {
        int which = tid >> 5, l = tid & 31;
        f4 s = which ? sredq[l] : sred[l];
        #pragma unroll
        for (int g = 1; g < 8; g++) s += which ? sredq[g * 32 + l] : sred[g * 32 + l];
        float* dstp = st1 + (b & 7) * 256 + which * 128;
        #pragma unroll
        for (int c = 0; c < 4; c++) atomicAdd(dstp + l * 4 + c, s[c]);
    }
}

__global__ __launch_bounds__(256) void k_bn1res(
        const float* __restrict__ st1,
        const float* __restrict__ gc, const float* __restrict__ bc,
        const float* __restrict__ x, float* __restrict__ aggxnew,
        float* __restrict__ st2, int N) {
    __shared__ f4 s1[256], s2[256];
    int tid = threadIdx.x;
    int sl = tid & 31, grp = tid >> 5;
    int d0 = sl * 4;
    float invN = 1.0f / (float)N;
    f4 mu = {0.f, 0.f, 0.f, 0.f}, sq = {0.f, 0.f, 0.f, 0.f};
    #pragma unroll
    for (int r = 0; r < 8; r++) {
        mu += *reinterpret_cast<const f4*>(st1 + r * 256 + d0);
        sq += *reinterpret_cast<const f4*>(st1 + r * 256 + 128 + d0);
    }
    f4 g4 = *reinterpret_cast<const f4*>(gc + d0);
    f4 b4 = *reinterpret_cast<const f4*>(bc + d0);
    f4 inv;
    #pragma unroll
    for (int c = 0; c < 4; c++) {
        float m = mu[c] * invN;
        mu[c] = m;
        inv[c] = rsqrtf(sq[c] * invN - m * m + 1e-5f);
    }
    f4 sa = {0.f, 0.f, 0.f, 0.f}, sb = {0.f, 0.f, 0.f, 0.f};
    for (int r = blockIdx.x * 8 + grp; r < N; r += gridDim.x * 8) {
        size_t idx = (size_t)r * D + d0;
        f4 v = *reinterpret_cast<const f4*>(aggxnew + idx);
        f4 xv = *reinterpret_cast<const f4*>(x + idx);
        f4 xn;
        #pragma unroll
        for (int c = 0; c < 4; c++) xn[c] = fmaf(g4[c] * (v[c] - mu[c]), inv[c], b4[c]) + xv[c];
        *reinterpret_cast<f4*>(aggxnew + idx) = xn;
        sa += xn;
        sb += xn * xn;
    }
    s1[tid] = sa;
    s2[tid] = sb;
    __syncthreads();
    if (tid < 64) {
        int which = tid >> 5, l = tid & 31;
        f4 acc = which ? s2[l] : s1[l];
        #pragma unroll
        for (int g = 1; g < 8; g++) acc += which ? s2[g * 32 + l] : s1[g * 32 + l];
        float* dstp = st2 + (blockIdx.x & 7) * 256 + which * 128;
        #pragma unroll
        for (int c = 0; c < 4; c++) atomicAdd(dstp + l * 4 + c, acc[c]);
    }
}

__global__ __launch_bounds__(256) void k_bn2relu(
        const float* __restrict__ st2,
        const float* __restrict__ gn, const float* __restrict__ bnb,
        const float* __restrict__ xnew, float* __restrict__ xout,
        unsigned short* __restrict__ xh, unsigned short* __restrict__ xl, int N) {
    int idx = blockIdx.x * blockDim.x + threadIdx.x;      // N*32 threads
    if (idx >= N * 32) return;
    int n = idx >> 5;
    int d0 = (idx & 31) * 4;
    float invN = 1.0f / (float)N;
    f4 mu = {0.f, 0.f, 0.f, 0.f}, sq = {0.f, 0.f, 0.f, 0.f};
    #pragma unroll
    for (int r = 0; r < 8; r++) {
        mu += *reinterpret_cast<const f4*>(st2 + r * 256 + d0);
        sq += *reinterpret_cast<const f4*>(st2 + r * 256 + 128 + d0);
    }
    f4 g4 = *reinterpret_cast<const f4*>(gn + d0);
    f4 b4 = *reinterpret_cast<const f4*>(bnb + d0);
    f4 v = *reinterpret_cast<const f4*>(xnew + (size_t)n * D + d0);
    f4 o;
    u16x4 h, l;
    #pragma unroll
    for (int c = 0; c < 4; c++) {
        float m = mu[c] * invN;
        float inv = rsqrtf(sq[c] * invN - m * m + 1e-5f);
        float t = fmaf(g4[c] * (v[c] - m), inv, b4[c]);
        t = fmaxf(t, 0.0f);
        o[c] = t;
        h[c] = f2bf(t);
        l[c] = f2bf(t - bf2f(h[c]));
    }
    *reinterpret_cast<f4*>(xout + (size_t)n * D + d0) = o;
    *reinterpret_cast<u16x4*>(xh + (size_t)n * D + d0) = h;
    *reinterpret_cast<u16x4*>(xl + (size_t)n * D + d0) = l;
}

// Per-graph feature sums: 8 blocks per graph, atomicAdd into gsum[G][D] (pre-zeroed)
__global__ __launch_bounds__(256) void k_pool(const float* __restrict__ x,
        float* __restrict__ gsum, int S) {
    __shared__ f4 s[256];
    int b = blockIdx.x;
    int g = b >> 3, sub = b & 7;
    int tid = threadIdx.x;
    int grp = tid >> 5, lane = tid & 31;
    int d0 = lane * 4;
    f4 a = {0.f, 0.f, 0.f, 0.f};
    for (int r = sub * 8 + grp; r < S; r += 64)
        a += *reinterpret_cast<const f4*>(x + ((size_t)g * S + r) * D + d0);
    s[tid] = a;
    __syncthreads();
    if (tid < 32) {
        f4 acc = s[tid];
        #pragma unroll
        for (int q = 1; q < 8; q++) acc += s[q * 32 + tid];
        #pragma unroll
        for (int c = 0; c < 4; c++) atomicAdd(&gsum[g * D + tid * 4 + c], acc[c]);
    }
}

// out[g] = relu(gmean@W1+b1) @ W2 + b2
__global__ __launch_bounds__(128) void k_mlp(const float* __restrict__ gsum,
        const float* __restrict__ W1, const float* __restrict__ b1,
        const float* __restrict__ W2, const float* __restrict__ b2,
        float* __restrict__ out, int S) {
    __shared__ float gm[D];
    __shared__ float red[128];
    int g = blockIdx.x, d = threadIdx.x;
    gm[d] = gsum[g * D + d] / (float)S;
    __syncthreads();
    float h = b1[d];
    #pragma unroll 8
    for (int k = 0; k < D; k++) h = fmaf(gm[k], W1[k * D + d], h);
    h = fmaxf(h, 0.0f);
    red[d] = h * W2[d];
    __syncthreads();
    for (int st = 64; st > 0; st >>= 1) {
        if (d < st) red[d] += red[d + st];
        __syncthreads();
    }
    if (d == 0) out[g] = red[0] + b2[0];
}

extern "C" void kernel_launch(void* const* d_in, const int* in_sizes, int n_in,
                              void* d_out, int out_size, void* d_ws, size_t ws_size,
                              hipStream_t stream) {
    const int*   z    = (const int*)d_in[0];
    const float* pos  = (const float*)d_in[1];
    const int*   eidx = (const int*)d_in[3];
    const float* emb  = (const float*)d_in[4];
    const float* Wf   = (const float*)d_in[5];
    const float* bf   = (const float*)d_in[6];
    const float* Ws   = (const float*)d_in[7];
    const float* bs   = (const float*)d_in[8];
    const float* gc   = (const float*)d_in[9];
    const float* bc   = (const float*)d_in[10];
    const float* gn   = (const float*)d_in[11];
    const float* bnb  = (const float*)d_in[12];
    const float* W1   = (const float*)d_in[13];
    const float* b1   = (const float*)d_in[14];
    const float* W2   = (const float*)d_in[15];
    const float* b2   = (const float*)d_in[16];

    int N = in_sizes[0];
    int E = in_sizes[3] / 2;
    int L = in_sizes[6] / D;
    int deg = E / N;
    int G = out_size;
    int S = N / G;

    const int* row = eidx;
    const int* col = eidx + E;

    float* ws = (float*)d_ws;
    size_t nd = (size_t)N * D;
    float* x    = ws;                  // [N][128]
    float* AfAs = x + nd;              // [N][256]
    float* BfBs = AfAs + 2 * nd;       // [N][256]
    float* agg  = BfBs + 2 * nd;       // [N][128] (fallback scratch)
    int2*  jd   = (int2*)(agg + nd);   // [E] packed (j, dist)
    unsigned short* xh  = (unsigned short*)(jd + E);
    unsigned short* xl  = xh + nd;
    unsigned short* Wth = xl + nd;                          // L*4*128*128 bf16
    unsigned short* Wtl = Wth + (size_t)L * 4 * D * D;
    float* stats = (float*)(Wtl + (size_t)L * 4 * D * D);   // L*4096 floats
    float* gsum  = stats + (size_t)L * 4096;                // G*128 floats

    hipMemsetAsync(stats, 0, ((size_t)L * 4096 + (size_t)G * D) * sizeof(float), stream);

    k_cvtW<<<(L * 4 * D * D + 255) / 256, 256, 0, stream>>>(Wf, Ws, Wth, Wtl, L);
    k_embed<<<(N * 32 + 255) / 256, 256, 0, stream>>>(z, emb, x, xh, xl, N);
    k_dist<<<(E + 255) / 256, 256, 0, stream>>>(row, col, pos, jd, E);

    for (int l = 0; l < L; ++l) {
        const float* Wfl = Wf + (size_t)l * 257 * D;
        const float* Wsl = Ws + (size_t)l * 257 * D;
        k_gemm_mfma<<<dim3(N / 128, 4), 256, 0, stream>>>(
            xh, xl, Wth + (size_t)l * 4 * D * D, Wtl + (size_t)l * 4 * D * D,
            bf + l * D, bs + l * D, AfAs, BfBs, S, G);

        const int2*  jdp  = jd;
        const float* afp  = AfAs;
        const float* bfp  = BfBs;
        const float* wfdp = Wfl + 256 * D;
        const float* wsdp = Wsl + 256 * D;
        const float* gcp  = gc + l * D;
        const float* bcp  = bc + l * D;
        const float* gnp  = gn + l * D;
        const float* bnbp = bnb + l * D;
        float* xp  = x;
        unsigned short* xhp = xh;
        unsigned short* xlp = xl;
        float* stp = stats + (size_t)l * 4096;
        void* args[] = {(void*)&jdp, (void*)&afp, (void*)&bfp, (void*)&wfdp, (void*)&wsdp,
                        (void*)&gcp, (void*)&bcp, (void*)&gnp, (void*)&bnbp,
                        (void*)&xp, (void*)&xhp, (void*)&xlp, (void*)&stp,
                        (void*)&N, (void*)&S, (void*)&G, (void*)&deg};
        hipError_t cerr = hipLaunchCooperativeKernel((void*)k_layer, dim3(LAYER_GRID),
                                                     dim3(256), args, 0, stream);
        if (cerr != hipSuccess) {
            // fallback: proven split path
            k_edges<<<(N + 7) / 8, 256, 0, stream>>>(jd, AfAs, BfBs, wfdp, wsdp,
                                                     agg, stp, N, S, G, deg);
            k_bn1res<<<2048, 256, 0, stream>>>(stp, gcp, bcp, x, agg, stp + 2048, N);
            k_bn2relu<<<(N * 32 + 255) / 256, 256, 0, stream>>>(stp + 2048, gnp, bnbp,
                                                                agg, x, xh, xl, N);
        }
    }
    k_pool<<<G * 8, 256, 0, stream>>>(x, gsum, S);
    k_mlp<<<G, 128, 0, stream>>>(gsum, W1, b1, W2, b2, (float*)d_out, S);
}

// Round 10
// 646.290 us; speedup vs baseline: 2.5562x; 2.5562x over previous
//
#include <hip/hip_runtime.h>
#include <math.h>

#define D 128
#define LOG2E 1.44269504f

typedef short bf16x8 __attribute__((ext_vector_type(8)));
typedef float f32x4 __attribute__((ext_vector_type(4)));
typedef float f4 __attribute__((ext_vector_type(4)));
typedef unsigned short u16x4 __attribute__((ext_vector_type(4)));

__device__ __forceinline__ unsigned short f2bf(float f) {
    unsigned int u = __float_as_uint(f);
    u += 0x7fff + ((u >> 16) & 1);   // round-to-nearest-even
    return (unsigned short)(u >> 16);
}
__device__ __forceinline__ float bf2f(unsigned short h) {
    return __uint_as_float(((unsigned int)h) << 16);
}
__device__ __forceinline__ bf16x8 load_bf8(const unsigned short* p) {
    return __builtin_bit_cast(bf16x8, *reinterpret_cast<const uint4*>(p));
}
// raw HW transcendentals (v_exp_f32 = 2^x, v_log_f32 = log2)
__device__ __forceinline__ float exp2_hw(float x) {
    float r; asm("v_exp_f32 %0, %1" : "=v"(r) : "v"(x)); return r;
}
__device__ __forceinline__ float log2_hw(float x) {
    float r; asm("v_log_f32 %0, %1" : "=v"(r) : "v"(x)); return r;
}

// graph-affine XCD swizzle: node-group gi -> node0, graph g lands on XCD g%8
__device__ __forceinline__ int swz_node0(int gi, int S, int G) {
    if ((G & 7) == 0 && (S & 7) == 0) {
        int xcd = gi & 7, i = gi >> 3;
        int bpg = S >> 3;
        int gr = i / bpg, li = i - gr * bpg;
        return (xcd + 8 * gr) * S + li * 8;
    }
    return gi * 8;
}

// x[n][d] = emb[z[n]][d]; also emit bf16 hi/lo split. float4 per thread.
__global__ __launch_bounds__(256) void k_embed(const int* __restrict__ z,
        const float* __restrict__ emb, float* __restrict__ x,
        unsigned short* __restrict__ xh, unsigned short* __restrict__ xl, int N) {
    int idx = blockIdx.x * blockDim.x + threadIdx.x;       // N*32 threads
    if (idx >= N * 32) return;
    int n = idx >> 5;
    int d0 = (idx & 31) * 4;
    f4 v = *reinterpret_cast<const f4*>(emb + (size_t)z[n] * D + d0);
    *reinterpret_cast<f4*>(x + (size_t)n * D + d0) = v;
    u16x4 h, l;
    #pragma unroll
    for (int c = 0; c < 4; c++) {
        h[c] = f2bf(v[c]);
        l[c] = f2bf(v[c] - bf2f(h[c]));
    }
    *reinterpret_cast<u16x4*>(xh + (size_t)n * D + d0) = h;
    *reinterpret_cast<u16x4*>(xl + (size_t)n * D + d0) = l;
}

// jd[e] = (row[e], bits(||pos[row]-pos[col]||)) packed
__global__ void k_dist(const int* __restrict__ row, const int* __restrict__ col,
                       const float* __restrict__ pos, int2* __restrict__ jd, int E) {
    int e = blockIdx.x * blockDim.x + threadIdx.x;
    if (e >= E) return;
    int r = row[e], c = col[e];
    float dx = pos[3 * r + 0] - pos[3 * c + 0];
    float dy = pos[3 * r + 1] - pos[3 * c + 1];
    float dz = pos[3 * r + 2] - pos[3 * c + 2];
    float dist = sqrtf(dx * dx + dy * dy + dz * dz);
    jd[e] = make_int2(r, __float_as_int(dist));
}

// Pre-transpose + bf16 hi/lo split all layer weights, PRE-SCALED for base-2 gate:
// f-path (mats 0,1) x (-log2e), s-path (mats 2,3) x (+log2e).
__global__ void k_cvtW(const float* __restrict__ Wf, const float* __restrict__ Ws,
                       unsigned short* __restrict__ Wth, unsigned short* __restrict__ Wtl,
                       int L) {
    int idx = blockIdx.x * blockDim.x + threadIdx.x;
    if (idx >= L * 4 * D * D) return;
    int k = idx & 127;
    int n = (idx >> 7) & 127;
    int mat = (idx >> 14) & 3;
    int l = idx >> 16;
    const float* src = (mat < 2) ? Wf : Ws;
    float scale = (mat < 2) ? -LOG2E : LOG2E;
    float v = scale * src[(size_t)l * 257 * D + (size_t)((mat & 1) * D + k) * D + n];
    unsigned short h = f2bf(v);
    Wth[idx] = h;
    Wtl[idx] = f2bf(v - bf2f(h));
}

// Split-bf16 MFMA GEMM (2-term: Xh*Wh + Xl*Wh), graph-affine XCD swizzle.
// Outputs interleaved: AfAs[N][256] = [Af|As], BfBs[N][256] = [Bf|Bs]  (pre-scaled)
__global__ __launch_bounds__(256) void k_gemm_mfma(
        const unsigned short* __restrict__ Xh, const unsigned short* __restrict__ Xl,
        const unsigned short* __restrict__ Wth, const unsigned short* __restrict__ Wtl,
        const float* __restrict__ bfl, const float* __restrict__ bsl,
        float* __restrict__ AfAs, float* __restrict__ BfBs, int S, int G) {
    int mat = blockIdx.y;                      // 0=Af 1=Bf 2=As 3=Bs
    float* O = ((mat & 1) ? BfBs : AfAs) + ((mat >> 1) ? 128 : 0);
    const float* bias = (mat == 0) ? bfl : (mat == 2) ? bsl : nullptr;
    float bsc = (mat == 0) ? -LOG2E : LOG2E;
    const unsigned short* Wh = Wth + (size_t)mat * D * D;

    int wave = threadIdx.x >> 6;
    int lane = threadIdx.x & 63;
    int r16 = lane & 15;
    int kg = lane >> 4;

    int xb = blockIdx.x;
    int tile0;
    if ((G & 7) == 0 && (S & 127) == 0) {
        int xcd = xb & 7, i = xb >> 3;
        int tpg = S >> 7;                       // 128-row tiles per graph
        int gi = i / tpg, t = i - gi * tpg;
        tile0 = (xcd + 8 * gi) * S + t * 128;   // graph g on XCD g%8
    } else tile0 = xb * 128;
    int row0 = tile0 + (wave >> 1) * 64;
    int wc = (wave & 1) * 64;

    f32x4 acc[4][4];
    #pragma unroll
    for (int m = 0; m < 4; m++)
        #pragma unroll
        for (int n = 0; n < 4; n++) acc[m][n] = (f32x4){0.f, 0.f, 0.f, 0.f};

    #pragma unroll
    for (int ks = 0; ks < 4; ++ks) {
        int k0 = ks * 32 + kg * 8;
        bf16x8 ah[4], al[4], bh[4];
        #pragma unroll
        for (int m = 0; m < 4; m++) {
            size_t off = (size_t)(row0 + m * 16 + r16) * D + k0;
            ah[m] = load_bf8(Xh + off);
            al[m] = load_bf8(Xl + off);
        }
        #pragma unroll
        for (int n = 0; n < 4; n++) {
            size_t off = (size_t)(wc + n * 16 + r16) * D + k0;
            bh[n] = load_bf8(Wh + off);
        }
        #pragma unroll
        for (int m = 0; m < 4; m++)
            #pragma unroll
            for (int n = 0; n < 4; n++) {
                acc[m][n] = __builtin_amdgcn_mfma_f32_16x16x32_bf16(ah[m], bh[n], acc[m][n], 0, 0, 0);
                acc[m][n] = __builtin_amdgcn_mfma_f32_16x16x32_bf16(al[m], bh[n], acc[m][n], 0, 0, 0);
            }
    }

    // C/D layout: col = lane&15, row = (lane>>4)*4 + reg
    #pragma unroll
    for (int n = 0; n < 4; n++) {
        int col = wc + n * 16 + r16;
        float bv = bias ? bias[col] * bsc : 0.0f;
        #pragma unroll
        for (int m = 0; m < 4; m++) {
            int rbase = row0 + m * 16 + kg * 4;
            #pragma unroll
            for (int r = 0; r < 4; r++)
                O[(size_t)(rbase + r) * 256 + col] = acc[m][n][r] + bv;
        }
    }
}

// Edge gate + aggregate + fused stats1. 8 nodes/block, 32 lanes/node, float4/lane.
__global__ __launch_bounds__(256) void k_edges(
        const int2* __restrict__ jd,
        const float* __restrict__ AfAs, const float* __restrict__ BfBs,
        const float* __restrict__ wfd, const float* __restrict__ wsd,
        float* __restrict__ agg, float* __restrict__ st1, int N, int S, int G, int deg) {
    __shared__ int2 jds[512];
    __shared__ f4 sred[256];
    __shared__ f4 sredq[256];
    int b = blockIdx.x;
    int node0 = swz_node0(b, S, G);
    int tid = threadIdx.x;
    int grp = tid >> 5, lane = tid & 31;
    bool use_lds = (8 * deg) <= 512;
    if (use_lds) {
        int tot = 8 * deg;
        int lim = (node0 + 8 <= N) ? tot : (N > node0 ? (N - node0) * deg : 0);
        for (int t = tid; t < lim; t += 256) jds[t] = jd[(size_t)node0 * deg + t];
    }
    __syncthreads();
    int node = node0 + grp;
    bool active = node < N;
    int d0 = lane * 4;
    f4 acc = {0.f, 0.f, 0.f, 0.f};
    if (active) {
        const f4 af4 = *reinterpret_cast<const f4*>(AfAs + (size_t)node * 256 + d0);
        const f4 as4 = *reinterpret_cast<const f4*>(AfAs + (size_t)node * 256 + 128 + d0);
        const f4 wf4 = *reinterpret_cast<const f4*>(wfd + d0) * (-LOG2E);
        const f4 ws4 = *reinterpret_cast<const f4*>(wsd + d0) * (LOG2E);
        const int2* jrow = use_lds ? (jds + grp * deg) : (jd + (size_t)node * deg);
        #pragma unroll 8
        for (int e = 0; e < deg; e++) {
            int2 p = jrow[e];
            float dst = __int_as_float(p.y);
            int off = (p.x << 8) + d0;          // 32-bit offset
            f4 bf4 = *reinterpret_cast<const f4*>(BfBs + off);
            f4 bs4 = *reinterpret_cast<const f4*>(BfBs + off + 128);
            #pragma unroll
            for (int c = 0; c < 4; c++) {
                float u2 = fmaf(dst, wf4[c], af4[c]) + bf4[c];   // -log2e*u
                float v2 = fmaf(dst, ws4[c], as4[c]) + bs4[c];   // +log2e*v
                float sE = exp2_hw(u2);
                float tE = exp2_hw(v2);
                float sg = __builtin_amdgcn_rcpf(1.0f + sE);     // sigmoid(u)
                float sp = log2_hw(1.0f + tE);                   // softplus(v)/ln2
                acc[c] = fmaf(sg, sp, acc[c]);
            }
        }
        *reinterpret_cast<f4*>(agg + (size_t)node * D + d0) = acc;
    }
    sred[tid] = acc;
    sredq[tid] = acc * acc;
    __syncthreads();
    if (tid < 64) {
        int which = tid >> 5, l = tid & 31;
        f4 s = which ? sredq[l] : sred[l];
        #pragma unroll
        for (int g = 1; g < 8; g++) s += which ? sredq[g * 32 + l] : sred[g * 32 + l];
        float* dstp = st1 + (b & 7) * 256 + which * 128;
        #pragma unroll
        for (int c = 0; c < 4; c++) atomicAdd(dstp + l * 4 + c, s[c]);
    }
}

// xnew = gc*(agg-mu1)*rsqrt(var1+eps)+bc+x (in place over agg), fused stats2.
// 2048 blocks, graph-affine swizzle, 8-way replicated stats2.
__global__ __launch_bounds__(256) void k_bn1res(
        const float* __restrict__ st1,
        const float* __restrict__ gc, const float* __restrict__ bc,
        const float* __restrict__ x, float* __restrict__ aggxnew,
        float* __restrict__ st2, int N, int S, int G) {
    __shared__ f4 s1[256], s2[256];
    int tid = threadIdx.x;
    int lane = tid & 31, grp = tid >> 5;
    int d0 = lane * 4;
    float invN = 1.0f / (float)N;
    f4 mu = {0.f, 0.f, 0.f, 0.f}, sq = {0.f, 0.f, 0.f, 0.f};
    #pragma unroll
    for (int r = 0; r < 8; r++) {
        mu += *reinterpret_cast<const f4*>(st1 + r * 256 + d0);
        sq += *reinterpret_cast<const f4*>(st1 + r * 256 + 128 + d0);
    }
    f4 g4 = *reinterpret_cast<const f4*>(gc + d0);
    f4 b4 = *reinterpret_cast<const f4*>(bc + d0);
    f4 inv;
    #pragma unroll
    for (int c = 0; c < 4; c++) {
        float m = mu[c] * invN;
        mu[c] = m;
        inv[c] = rsqrtf(sq[c] * invN - m * m + 1e-5f);
    }
    int NG = (N + 7) >> 3;
    f4 sa = {0.f, 0.f, 0.f, 0.f}, sb = {0.f, 0.f, 0.f, 0.f};
    #pragma unroll 2
    for (int t = 0; t < 2; t++) {
        int gi = blockIdx.x + t * 2048;
        if (gi >= NG) break;
        int r = swz_node0(gi, S, G) + grp;
        if (r >= N) continue;
        size_t idx = (size_t)r * D + d0;
        f4 v = *reinterpret_cast<const f4*>(aggxnew + idx);
        f4 xv = *reinterpret_cast<const f4*>(x + idx);
        f4 xn;
        #pragma unroll
        for (int c = 0; c < 4; c++) xn[c] = fmaf(g4[c] * (v[c] - mu[c]), inv[c], b4[c]) + xv[c];
        *reinterpret_cast<f4*>(aggxnew + idx) = xn;
        sa += xn;
        sb += xn * xn;
    }
    s1[tid] = sa;
    s2[tid] = sb;
    __syncthreads();
    if (tid < 64) {
        int which = tid >> 5, l = tid & 31;
        f4 acc = which ? s2[l] : s1[l];
        #pragma unroll
        for (int g = 1; g < 8; g++) acc += which ? s2[g * 32 + l] : s1[g * 32 + l];
        float* dstp = st2 + (blockIdx.x & 7) * 256 + which * 128;
        #pragma unroll
        for (int c = 0; c < 4; c++) atomicAdd(dstp + l * 4 + c, acc[c]);
    }
}

// x = relu(gn*(xnew-mu2)*rsqrt(var2+eps)+bnb); emit bf16 hi/lo.
// NG blocks, 8 nodes/block, graph-affine swizzle; stats2 from 8 replicated slots.
__global__ __launch_bounds__(256) void k_bn2relu(
        const float* __restrict__ st2,
        const float* __restrict__ gn, const float* __restrict__ bnb,
        const float* __restrict__ xnew, float* __restrict__ xout,
        unsigned short* __restrict__ xh, unsigned short* __restrict__ xl,
        int N, int S, int G) {
    int tid = threadIdx.x;
    int lane = tid & 31, grp = tid >> 5;
    int d0 = lane * 4;
    int node = swz_node0(blockIdx.x, S, G) + grp;
    if (node >= N) return;
    float invN = 1.0f / (float)N;
    f4 mu = {0.f, 0.f, 0.f, 0.f}, sq = {0.f, 0.f, 0.f, 0.f};
    #pragma unroll
    for (int r = 0; r < 8; r++) {
        mu += *reinterpret_cast<const f4*>(st2 + r * 256 + d0);
        sq += *reinterpret_cast<const f4*>(st2 + r * 256 + 128 + d0);
    }
    f4 g4 = *reinterpret_cast<const f4*>(gn + d0);
    f4 b4 = *reinterpret_cast<const f4*>(bnb + d0);
    f4 v = *reinterpret_cast<const f4*>(xnew + (size_t)node * D + d0);
    f4 o;
    u16x4 h, l;
    #pragma unroll
    for (int c = 0; c < 4; c++) {
        float m = mu[c] * invN;
        float inv = rsqrtf(sq[c] * invN - m * m + 1e-5f);
        float t = fmaf(g4[c] * (v[c] - m), inv, b4[c]);
        t = fmaxf(t, 0.0f);
        o[c] = t;
        h[c] = f2bf(t);
        l[c] = f2bf(t - bf2f(h[c]));
    }
    *reinterpret_cast<f4*>(xout + (size_t)node * D + d0) = o;
    *reinterpret_cast<u16x4*>(xh + (size_t)node * D + d0) = h;
    *reinterpret_cast<u16x4*>(xl + (size_t)node * D + d0) = l;
}

// Per-graph feature sums: 8 blocks per graph (g = b&31 so XCD matches g%8)
__global__ __launch_bounds__(256) void k_pool(const float* __restrict__ x,
        float* __restrict__ gsum, int S, int G) {
    __shared__ f4 s[256];
    int b = blockIdx.x;
    int g, sub;
    if ((G & 31) == 0) { g = b & 31; sub = b >> 5; }
    else               { g = b >> 3; sub = b & 7; }
    int tid = threadIdx.x;
    int grp = tid >> 5, lane = tid & 31;
    int d0 = lane * 4;
    f4 a = {0.f, 0.f, 0.f, 0.f};
    for (int r = sub * 8 + grp; r < S; r += 64)
        a += *reinterpret_cast<const f4*>(x + ((size_t)g * S + r) * D + d0);
    s[tid] = a;
    __syncthreads();
    if (tid < 32) {
        f4 acc = s[tid];
        #pragma unroll
        for (int q = 1; q < 8; q++) acc += s[q * 32 + tid];
        #pragma unroll
        for (int c = 0; c < 4; c++) atomicAdd(&gsum[g * D + tid * 4 + c], acc[c]);
    }
}

// out[g] = relu(gmean@W1+b1) @ W2 + b2
__global__ __launch_bounds__(128) void k_mlp(const float* __restrict__ gsum,
        const float* __restrict__ W1, const float* __restrict__ b1,
        const float* __restrict__ W2, const float* __restrict__ b2,
        float* __restrict__ out, int S) {
    __shared__ float gm[D];
    __shared__ float red[128];
    int g = blockIdx.x, d = threadIdx.x;
    gm[d] = gsum[g * D + d] / (float)S;
    __syncthreads();
    float h = b1[d];
    #pragma unroll 8
    for (int k = 0; k < D; k++) h = fmaf(gm[k], W1[k * D + d], h);
    h = fmaxf(h, 0.0f);
    red[d] = h * W2[d];
    __syncthreads();
    for (int st = 64; st > 0; st >>= 1) {
        if (d < st) red[d] += red[d + st];
        __syncthreads();
    }
    if (d == 0) out[g] = red[0] + b2[0];
}

extern "C" void kernel_launch(void* const* d_in, const int* in_sizes, int n_in,
                              void* d_out, int out_size, void* d_ws, size_t ws_size,
                              hipStream_t stream) {
    const int*   z    = (const int*)d_in[0];
    const float* pos  = (const float*)d_in[1];
    const int*   eidx = (const int*)d_in[3];
    const float* emb  = (const float*)d_in[4];
    const float* Wf   = (const float*)d_in[5];
    const float* bf   = (const float*)d_in[6];
    const float* Ws   = (const float*)d_in[7];
    const float* bs   = (const float*)d_in[8];
    const float* gc   = (const float*)d_in[9];
    const float* bc   = (const float*)d_in[10];
    const float* gn   = (const float*)d_in[11];
    const float* bnb  = (const float*)d_in[12];
    const float* W1   = (const float*)d_in[13];
    const float* b1   = (const float*)d_in[14];
    const float* W2   = (const float*)d_in[15];
    const float* b2   = (const float*)d_in[16];

    int N = in_sizes[0];
    int E = in_sizes[3] / 2;
    int L = in_sizes[6] / D;
    int deg = E / N;
    int G = out_size;
    int S = N / G;

    const int* row = eidx;
    const int* col = eidx + E;

    float* ws = (float*)d_ws;
    size_t nd = (size_t)N * D;
    float* x    = ws;                  // [N][128]
    float* AfAs = x + nd;              // [N][256]
    float* BfBs = AfAs + 2 * nd;       // [N][256]
    float* agg  = BfBs + 2 * nd;       // [N][128], becomes xnew in place
    int2*  jd   = (int2*)(agg + nd);   // [E] packed (j, dist)
    unsigned short* xh  = (unsigned short*)(jd + E);
    unsigned short* xl  = xh + nd;
    unsigned short* Wth = xl + nd;                          // L*4*128*128 bf16
    unsigned short* Wtl = Wth + (size_t)L * 4 * D * D;
    float* stats = (float*)(Wtl + (size_t)L * 4 * D * D);   // L*4096 floats
    float* gsum  = stats + (size_t)L * 4096;                // G*128 floats

    hipMemsetAsync(stats, 0, ((size_t)L * 4096 + (size_t)G * D) * sizeof(float), stream);

    k_cvtW<<<(L * 4 * D * D + 255) / 256, 256, 0, stream>>>(Wf, Ws, Wth, Wtl, L);
    k_embed<<<(N * 32 + 255) / 256, 256, 0, stream>>>(z, emb, x, xh, xl, N);
    k_dist<<<(E + 255) / 256, 256, 0, stream>>>(row, col, pos, jd, E);

    int NG = (N + 7) / 8;
    for (int l = 0; l < L; ++l) {
        const float* Wfl = Wf + (size_t)l * 257 * D;
        const float* Wsl = Ws + (size_t)l * 257 * D;
        float* stp = stats + (size_t)l * 4096;
        k_gemm_mfma<<<dim3(N / 128, 4), 256, 0, stream>>>(
            xh, xl, Wth + (size_t)l * 4 * D * D, Wtl + (size_t)l * 4 * D * D,
            bf + l * D, bs + l * D, AfAs, BfBs, S, G);
        k_edges<<<NG, 256, 0, stream>>>(jd, AfAs, BfBs, Wfl + 256 * D, Wsl + 256 * D,
                                        agg, stp, N, S, G, deg);
        k_bn1res<<<2048, 256, 0, stream>>>(stp, gc + l * D, bc + l * D,
                                           x, agg, stp + 2048, N, S, G);
        k_bn2relu<<<NG, 256, 0, stream>>>(stp + 2048, gn + l * D, bnb + l * D,
                                          agg, x, xh, xl, N, S, G);
    }
    k_pool<<<G * 8, 256, 0, stream>>>(x, gsum, S, G);
    k_mlp<<<G, 128, 0, stream>>>(gsum, W1, b1, W2, b2, (float*)d_out, S);
}

// Round 11
// 586.868 us; speedup vs baseline: 2.8150x; 1.1013x over previous
//
#include <hip/hip_runtime.h>
#include <math.h>

#define D 128
#define LOG2E 1.44269504f

typedef short bf16x8 __attribute__((ext_vector_type(8)));
typedef float f32x4 __attribute__((ext_vector_type(4)));
typedef float f4 __attribute__((ext_vector_type(4)));
typedef unsigned short u16x4 __attribute__((ext_vector_type(4)));

__device__ __forceinline__ unsigned short f2bf(float f) {
    unsigned int u = __float_as_uint(f);
    u += 0x7fff + ((u >> 16) & 1);   // round-to-nearest-even
    return (unsigned short)(u >> 16);
}
__device__ __forceinline__ float bf2f(unsigned short h) {
    return __uint_as_float(((unsigned int)h) << 16);
}
__device__ __forceinline__ bf16x8 load_bf8(const unsigned short* p) {
    return __builtin_bit_cast(bf16x8, *reinterpret_cast<const uint4*>(p));
}
// raw HW transcendentals (v_exp_f32 = 2^x, v_log_f32 = log2)
__device__ __forceinline__ float exp2_hw(float x) {
    float r; asm("v_exp_f32 %0, %1" : "=v"(r) : "v"(x)); return r;
}
__device__ __forceinline__ float log2_hw(float x) {
    float r; asm("v_log_f32 %0, %1" : "=v"(r) : "v"(x)); return r;
}

// graph-affine XCD swizzle: node-group gi -> node0, graph g lands on XCD g%8
__device__ __forceinline__ int swz_node0(int gi, int S, int G) {
    if ((G & 7) == 0 && (S & 7) == 0) {
        int xcd = gi & 7, i = gi >> 3;
        int bpg = S >> 3;
        int gr = i / bpg, li = i - gr * bpg;
        return (xcd + 8 * gr) * S + li * 8;
    }
    return gi * 8;
}

// x[n][d] = emb[z[n]][d]; also emit bf16 hi/lo split. float4 per thread.
__global__ __launch_bounds__(256) void k_embed(const int* __restrict__ z,
        const float* __restrict__ emb, float* __restrict__ x,
        unsigned short* __restrict__ xh, unsigned short* __restrict__ xl, int N) {
    int idx = blockIdx.x * blockDim.x + threadIdx.x;       // N*32 threads
    if (idx >= N * 32) return;
    int n = idx >> 5;
    int d0 = (idx & 31) * 4;
    f4 v = *reinterpret_cast<const f4*>(emb + (size_t)z[n] * D + d0);
    *reinterpret_cast<f4*>(x + (size_t)n * D + d0) = v;
    u16x4 h, l;
    #pragma unroll
    for (int c = 0; c < 4; c++) {
        h[c] = f2bf(v[c]);
        l[c] = f2bf(v[c] - bf2f(h[c]));
    }
    *reinterpret_cast<u16x4*>(xh + (size_t)n * D + d0) = h;
    *reinterpret_cast<u16x4*>(xl + (size_t)n * D + d0) = l;
}

// jd[e] = (row[e], bits(||pos[row]-pos[col]||)) packed
__global__ void k_dist(const int* __restrict__ row, const int* __restrict__ col,
                       const float* __restrict__ pos, int2* __restrict__ jd, int E) {
    int e = blockIdx.x * blockDim.x + threadIdx.x;
    if (e >= E) return;
    int r = row[e], c = col[e];
    float dx = pos[3 * r + 0] - pos[3 * c + 0];
    float dy = pos[3 * r + 1] - pos[3 * c + 1];
    float dz = pos[3 * r + 2] - pos[3 * c + 2];
    float dist = sqrtf(dx * dx + dy * dy + dz * dz);
    jd[e] = make_int2(r, __float_as_int(dist));
}

// Pre-transpose + bf16 hi/lo split all layer weights, PRE-SCALED for base-2 gate:
// f-path (mats 0,1) x (-log2e), s-path (mats 2,3) x (+log2e).
__global__ void k_cvtW(const float* __restrict__ Wf, const float* __restrict__ Ws,
                       unsigned short* __restrict__ Wth, unsigned short* __restrict__ Wtl,
                       int L) {
    int idx = blockIdx.x * blockDim.x + threadIdx.x;
    if (idx >= L * 4 * D * D) return;
    int k = idx & 127;
    int n = (idx >> 7) & 127;
    int mat = (idx >> 14) & 3;
    int l = idx >> 16;
    const float* src = (mat < 2) ? Wf : Ws;
    float scale = (mat < 2) ? -LOG2E : LOG2E;
    float v = scale * src[(size_t)l * 257 * D + (size_t)((mat & 1) * D + k) * D + n];
    unsigned short h = f2bf(v);
    Wth[idx] = h;
    Wtl[idx] = f2bf(v - bf2f(h));
}

// Split-bf16 MFMA GEMM (2-term: Xh*Wh + Xl*Wh), graph-affine XCD swizzle.
// Outputs interleaved: AfAs[N][256] = [Af|As], BfBs[N][256] = [Bf|Bs]  (pre-scaled)
__global__ __launch_bounds__(256) void k_gemm_mfma(
        const unsigned short* __restrict__ Xh, const unsigned short* __restrict__ Xl,
        const unsigned short* __restrict__ Wth, const unsigned short* __restrict__ Wtl,
        const float* __restrict__ bfl, const float* __restrict__ bsl,
        float* __restrict__ AfAs, float* __restrict__ BfBs, int S, int G) {
    int mat = blockIdx.y;                      // 0=Af 1=Bf 2=As 3=Bs
    float* O = ((mat & 1) ? BfBs : AfAs) + ((mat >> 1) ? 128 : 0);
    const float* bias = (mat == 0) ? bfl : (mat == 2) ? bsl : nullptr;
    float bsc = (mat == 0) ? -LOG2E : LOG2E;
    const unsigned short* Wh = Wth + (size_t)mat * D * D;

    int wave = threadIdx.x >> 6;
    int lane = threadIdx.x & 63;
    int r16 = lane & 15;
    int kg = lane >> 4;

    int xb = blockIdx.x;
    int tile0;
    if ((G & 7) == 0 && (S & 127) == 0) {
        int xcd = xb & 7, i = xb >> 3;
        int tpg = S >> 7;                       // 128-row tiles per graph
        int gi = i / tpg, t = i - gi * tpg;
        tile0 = (xcd + 8 * gi) * S + t * 128;   // graph g on XCD g%8
    } else tile0 = xb * 128;
    int row0 = tile0 + (wave >> 1) * 64;
    int wc = (wave & 1) * 64;

    f32x4 acc[4][4];
    #pragma unroll
    for (int m = 0; m < 4; m++)
        #pragma unroll
        for (int n = 0; n < 4; n++) acc[m][n] = (f32x4){0.f, 0.f, 0.f, 0.f};

    #pragma unroll
    for (int ks = 0; ks < 4; ++ks) {
        int k0 = ks * 32 + kg * 8;
        bf16x8 ah[4], al[4], bh[4];
        #pragma unroll
        for (int m = 0; m < 4; m++) {
            size_t off = (size_t)(row0 + m * 16 + r16) * D + k0;
            ah[m] = load_bf8(Xh + off);
            al[m] = load_bf8(Xl + off);
        }
        #pragma unroll
        for (int n = 0; n < 4; n++) {
            size_t off = (size_t)(wc + n * 16 + r16) * D + k0;
            bh[n] = load_bf8(Wh + off);
        }
        #pragma unroll
        for (int m = 0; m < 4; m++)
            #pragma unroll
            for (int n = 0; n < 4; n++) {
                acc[m][n] = __builtin_amdgcn_mfma_f32_16x16x32_bf16(ah[m], bh[n], acc[m][n], 0, 0, 0);
                acc[m][n] = __builtin_amdgcn_mfma_f32_16x16x32_bf16(al[m], bh[n], acc[m][n], 0, 0, 0);
            }
    }

    // C/D layout: col = lane&15, row = (lane>>4)*4 + reg
    #pragma unroll
    for (int n = 0; n < 4; n++) {
        int col = wc + n * 16 + r16;
        float bv = bias ? bias[col] * bsc : 0.0f;
        #pragma unroll
        for (int m = 0; m < 4; m++) {
            int rbase = row0 + m * 16 + kg * 4;
            #pragma unroll
            for (int r = 0; r < 4; r++)
                O[(size_t)(rbase + r) * 256 + col] = acc[m][n][r] + bv;
        }
    }
}

// Edge gate + aggregate + fused 5-way stats (agg, agg^2, x, x^2, agg*x).
// 8 nodes/block, 32 lanes/node, float4/lane; graph-affine XCD swizzle.
// st slot layout per block-group (b&7): 640 floats =
//   [sum_agg(128) | sum_agg2(128) | sum_x(128) | sum_x2(128) | sum_aggx(128)]
__global__ __launch_bounds__(256) void k_edges(
        const int2* __restrict__ jd,
        const float* __restrict__ AfAs, const float* __restrict__ BfBs,
        const float* __restrict__ wfd, const float* __restrict__ wsd,
        const float* __restrict__ x,
        float* __restrict__ agg, float* __restrict__ st, int N, int S, int G, int deg) {
    __shared__ int2 jds[512];
    __shared__ f4 sred[256];
    __shared__ f4 sredq[256];
    int b = blockIdx.x;
    int node0 = swz_node0(b, S, G);
    int tid = threadIdx.x;
    int grp = tid >> 5, lane = tid & 31;
    bool use_lds = (8 * deg) <= 512;
    if (use_lds) {
        int tot = 8 * deg;
        int lim = (node0 + 8 <= N) ? tot : (N > node0 ? (N - node0) * deg : 0);
        for (int t = tid; t < lim; t += 256) jds[t] = jd[(size_t)node0 * deg + t];
    }
    __syncthreads();
    int node = node0 + grp;
    bool active = node < N;
    int d0 = lane * 4;
    f4 acc = {0.f, 0.f, 0.f, 0.f};
    f4 xv = {0.f, 0.f, 0.f, 0.f};
    if (active) {
        const f4 af4 = *reinterpret_cast<const f4*>(AfAs + (size_t)node * 256 + d0);
        const f4 as4 = *reinterpret_cast<const f4*>(AfAs + (size_t)node * 256 + 128 + d0);
        const f4 wf4 = *reinterpret_cast<const f4*>(wfd + d0) * (-LOG2E);
        const f4 ws4 = *reinterpret_cast<const f4*>(wsd + d0) * (LOG2E);
        const int2* jrow = use_lds ? (jds + grp * deg) : (jd + (size_t)node * deg);
        #pragma unroll 8
        for (int e = 0; e < deg; e++) {
            int2 p = jrow[e];
            float dst = __int_as_float(p.y);
            int off = (p.x << 8) + d0;          // 32-bit offset
            f4 bf4 = *reinterpret_cast<const f4*>(BfBs + off);
            f4 bs4 = *reinterpret_cast<const f4*>(BfBs + off + 128);
            #pragma unroll
            for (int c = 0; c < 4; c++) {
                float u2 = fmaf(dst, wf4[c], af4[c]) + bf4[c];   // -log2e*u
                float v2 = fmaf(dst, ws4[c], as4[c]) + bs4[c];   // +log2e*v
                float sE = exp2_hw(u2);
                float tE = exp2_hw(v2);
                float sg = __builtin_amdgcn_rcpf(1.0f + sE);     // sigmoid(u)
                float sp = log2_hw(1.0f + tE);                   // softplus(v)/ln2
                acc[c] = fmaf(sg, sp, acc[c]);
            }
        }
        *reinterpret_cast<f4*>(agg + (size_t)node * D + d0) = acc;
        xv = *reinterpret_cast<const f4*>(x + (size_t)node * D + d0);
    }
    float* stb = st + (b & 7) * 640;
    // round 1: sum_agg, sum_agg2
    sred[tid] = acc;
    sredq[tid] = acc * acc;
    __syncthreads();
    if (tid < 64) {
        int which = tid >> 5, l = tid & 31;
        f4 s = which ? sredq[l] : sred[l];
        #pragma unroll
        for (int g = 1; g < 8; g++) s += which ? sredq[g * 32 + l] : sred[g * 32 + l];
        float* dstp = stb + which * 128;
        #pragma unroll
        for (int c = 0; c < 4; c++) atomicAdd(dstp + l * 4 + c, s[c]);
    }
    __syncthreads();
    // round 2: sum_x, sum_x2
    sred[tid] = xv;
    sredq[tid] = xv * xv;
    __syncthreads();
    if (tid < 64) {
        int which = tid >> 5, l = tid & 31;
        f4 s = which ? sredq[l] : sred[l];
        #pragma unroll
        for (int g = 1; g < 8; g++) s += which ? sredq[g * 32 + l] : sred[g * 32 + l];
        float* dstp = stb + 256 + which * 128;
        #pragma unroll
        for (int c = 0; c < 4; c++) atomicAdd(dstp + l * 4 + c, s[c]);
    }
    __syncthreads();
    // round 3: sum_agg*x
    sred[tid] = acc * xv;
    __syncthreads();
    if (tid < 32) {
        f4 s = sred[tid];
        #pragma unroll
        for (int g = 1; g < 8; g++) s += sred[g * 32 + tid];
        #pragma unroll
        for (int c = 0; c < 4; c++) atomicAdd(stb + 512 + tid * 4 + c, s[c]);
    }
}

// Fused BN1+residual+BN2+ReLU, stats2 computed ALGEBRAICALLY:
//   xn = A*agg + C + x,  A = gc*inv1, C = bc - A*mu1
//   mu2 = bc + mean(x)   (A-terms cancel exactly)
//   E[xn^2] = (A^2*Sagg2 + 2AC*Sagg + 2A*Saggx + 2C*Sx + Sx2)/N + C^2
// One pass: read agg + x, write x, xh, xl.  NG blocks, 8 nodes/block, swizzled.
__global__ __launch_bounds__(256) void k_bnfused(
        const float* __restrict__ st,
        const float* __restrict__ gc, const float* __restrict__ bc,
        const float* __restrict__ gn, const float* __restrict__ bnb,
        const float* __restrict__ agg, float* __restrict__ x,
        unsigned short* __restrict__ xh, unsigned short* __restrict__ xl,
        int N, int S, int G) {
    int tid = threadIdx.x;
    int lane = tid & 31, grp = tid >> 5;
    int d0 = lane * 4;
    int node = swz_node0(blockIdx.x, S, G) + grp;
    if (node >= N) return;
    float invN = 1.0f / (float)N;
    f4 Sa = {0.f, 0.f, 0.f, 0.f}, Sa2 = {0.f, 0.f, 0.f, 0.f};
    f4 Sx = {0.f, 0.f, 0.f, 0.f}, Sx2 = {0.f, 0.f, 0.f, 0.f}, Sax = {0.f, 0.f, 0.f, 0.f};
    #pragma unroll
    for (int r = 0; r < 8; r++) {
        const float* stb = st + r * 640;
        Sa  += *reinterpret_cast<const f4*>(stb + d0);
        Sa2 += *reinterpret_cast<const f4*>(stb + 128 + d0);
        Sx  += *reinterpret_cast<const f4*>(stb + 256 + d0);
        Sx2 += *reinterpret_cast<const f4*>(stb + 384 + d0);
        Sax += *reinterpret_cast<const f4*>(stb + 512 + d0);
    }
    f4 g1 = *reinterpret_cast<const f4*>(gc + d0);
    f4 b1v = *reinterpret_cast<const f4*>(bc + d0);
    f4 g2 = *reinterpret_cast<const f4*>(gn + d0);
    f4 b2v = *reinterpret_cast<const f4*>(bnb + d0);
    f4 A, C, mu2, inv2;
    #pragma unroll
    for (int c = 0; c < 4; c++) {
        float m1 = Sa[c] * invN;
        float var1 = Sa2[c] * invN - m1 * m1;
        float i1 = rsqrtf(var1 + 1e-5f);
        float a = g1[c] * i1;
        float cc = b1v[c] - a * m1;
        float mx = Sx[c] * invN;
        float m2 = b1v[c] + mx;
        float e2 = (a * a * Sa2[c] + 2.f * a * cc * Sa[c] + 2.f * a * Sax[c]
                    + 2.f * cc * Sx[c] + Sx2[c]) * invN + cc * cc;
        float var2 = e2 - m2 * m2;
        A[c] = a; C[c] = cc; mu2[c] = m2;
        inv2[c] = rsqrtf(var2 + 1e-5f);
    }
    size_t idx = (size_t)node * D + d0;
    f4 av = *reinterpret_cast<const f4*>(agg + idx);
    f4 xv = *reinterpret_cast<const f4*>(x + idx);
    f4 o;
    u16x4 h, l;
    #pragma unroll
    for (int c = 0; c < 4; c++) {
        float xn = fmaf(A[c], av[c], C[c]) + xv[c];
        float t = fmaf(g2[c] * (xn - mu2[c]), inv2[c], b2v[c]);
        t = fmaxf(t, 0.0f);
        o[c] = t;
        h[c] = f2bf(t);
        l[c] = f2bf(t - bf2f(h[c]));
    }
    *reinterpret_cast<f4*>(x + idx) = o;
    *reinterpret_cast<u16x4*>(xh + idx) = h;
    *reinterpret_cast<u16x4*>(xl + idx) = l;
}

// Per-graph feature sums: 8 blocks per graph (g = b&31 so XCD matches g%8)
__global__ __launch_bounds__(256) void k_pool(const float* __restrict__ x,
        float* __restrict__ gsum, int S, int G) {
    __shared__ f4 s[256];
    int b = blockIdx.x;
    int g, sub;
    if ((G & 31) == 0) { g = b & 31; sub = b >> 5; }
    else               { g = b >> 3; sub = b & 7; }
    int tid = threadIdx.x;
    int grp = tid >> 5, lane = tid & 31;
    int d0 = lane * 4;
    f4 a = {0.f, 0.f, 0.f, 0.f};
    for (int r = sub * 8 + grp; r < S; r += 64)
        a += *reinterpret_cast<const f4*>(x + ((size_t)g * S + r) * D + d0);
    s[tid] = a;
    __syncthreads();
    if (tid < 32) {
        f4 acc = s[tid];
        #pragma unroll
        for (int q = 1; q < 8; q++) acc += s[q * 32 + tid];
        #pragma unroll
        for (int c = 0; c < 4; c++) atomicAdd(&gsum[g * D + tid * 4 + c], acc[c]);
    }
}

// out[g] = relu(gmean@W1+b1) @ W2 + b2
__global__ __launch_bounds__(128) void k_mlp(const float* __restrict__ gsum,
        const float* __restrict__ W1, const float* __restrict__ b1,
        const float* __restrict__ W2, const float* __restrict__ b2,
        float* __restrict__ out, int S) {
    __shared__ float gm[D];
    __shared__ float red[128];
    int g = blockIdx.x, d = threadIdx.x;
    gm[d] = gsum[g * D + d] / (float)S;
    __syncthreads();
    float h = b1[d];
    #pragma unroll 8
    for (int k = 0; k < D; k++) h = fmaf(gm[k], W1[k * D + d], h);
    h = fmaxf(h, 0.0f);
    red[d] = h * W2[d];
    __syncthreads();
    for (int st = 64; st > 0; st >>= 1) {
        if (d < st) red[d] += red[d + st];
        __syncthreads();
    }
    if (d == 0) out[g] = red[0] + b2[0];
}

extern "C" void kernel_launch(void* const* d_in, const int* in_sizes, int n_in,
                              void* d_out, int out_size, void* d_ws, size_t ws_size,
                              hipStream_t stream) {
    const int*   z    = (const int*)d_in[0];
    const float* pos  = (const float*)d_in[1];
    const int*   eidx = (const int*)d_in[3];
    const float* emb  = (const float*)d_in[4];
    const float* Wf   = (const float*)d_in[5];
    const float* bf   = (const float*)d_in[6];
    const float* Ws   = (const float*)d_in[7];
    const float* bs   = (const float*)d_in[8];
    const float* gc   = (const float*)d_in[9];
    const float* bc   = (const float*)d_in[10];
    const float* gn   = (const float*)d_in[11];
    const float* bnb  = (const float*)d_in[12];
    const float* W1   = (const float*)d_in[13];
    const float* b1   = (const float*)d_in[14];
    const float* W2   = (const float*)d_in[15];
    const float* b2   = (const float*)d_in[16];

    int N = in_sizes[0];
    int E = in_sizes[3] / 2;
    int L = in_sizes[6] / D;
    int deg = E / N;
    int G = out_size;
    int S = N / G;

    const int* row = eidx;
    const int* col = eidx + E;

    float* ws = (float*)d_ws;
    size_t nd = (size_t)N * D;
    float* x    = ws;                  // [N][128]
    float* AfAs = x + nd;              // [N][256]
    float* BfBs = AfAs + 2 * nd;       // [N][256]
    float* agg  = BfBs + 2 * nd;       // [N][128]
    int2*  jd   = (int2*)(agg + nd);   // [E] packed (j, dist)
    unsigned short* xh  = (unsigned short*)(jd + E);
    unsigned short* xl  = xh + nd;
    unsigned short* Wth = xl + nd;                          // L*4*128*128 bf16
    unsigned short* Wtl = Wth + (size_t)L * 4 * D * D;
    float* stats = (float*)(Wtl + (size_t)L * 4 * D * D);   // L * 8*640 floats
    float* gsum  = stats + (size_t)L * 5120;                // G*128 floats

    hipMemsetAsync(stats, 0, ((size_t)L * 5120 + (size_t)G * D) * sizeof(float), stream);

    k_cvtW<<<(L * 4 * D * D + 255) / 256, 256, 0, stream>>>(Wf, Ws, Wth, Wtl, L);
    k_embed<<<(N * 32 + 255) / 256, 256, 0, stream>>>(z, emb, x, xh, xl, N);
    k_dist<<<(E + 255) / 256, 256, 0, stream>>>(row, col, pos, jd, E);

    int NG = (N + 7) / 8;
    for (int l = 0; l < L; ++l) {
        const float* Wfl = Wf + (size_t)l * 257 * D;
        const float* Wsl = Ws + (size_t)l * 257 * D;
        float* stp = stats + (size_t)l * 5120;
        k_gemm_mfma<<<dim3(N / 128, 4), 256, 0, stream>>>(
            xh, xl, Wth + (size_t)l * 4 * D * D, Wtl + (size_t)l * 4 * D * D,
            bf + l * D, bs + l * D, AfAs, BfBs, S, G);
        k_edges<<<NG, 256, 0, stream>>>(jd, AfAs, BfBs, Wfl + 256 * D, Wsl + 256 * D,
                                        x, agg, stp, N, S, G, deg);
        k_bnfused<<<NG, 256, 0, stream>>>(stp, gc + l * D, bc + l * D,
                                          gn + l * D, bnb + l * D,
                                          agg, x, xh, xl, N, S, G);
    }
    k_pool<<<G * 8, 256, 0, stream>>>(x, gsum, S, G);
    k_mlp<<<G, 128, 0, stream>>>(gsum, W1, b1, W2, b2, (float*)d_out, S);
}

// Round 12
// 550.436 us; speedup vs baseline: 3.0014x; 1.0662x over previous
//
#include <hip/hip_runtime.h>
#include <math.h>

#define D 128
#define LOG2E 1.44269504f

typedef short bf16x8 __attribute__((ext_vector_type(8)));
typedef float f32x4 __attribute__((ext_vector_type(4)));
typedef float f4 __attribute__((ext_vector_type(4)));
typedef unsigned short u16x4 __attribute__((ext_vector_type(4)));

__device__ __forceinline__ unsigned short f2bf(float f) {
    unsigned int u = __float_as_uint(f);
    u += 0x7fff + ((u >> 16) & 1);   // round-to-nearest-even
    return (unsigned short)(u >> 16);
}
__device__ __forceinline__ float bf2f(unsigned short h) {
    return __uint_as_float(((unsigned int)h) << 16);
}
__device__ __forceinline__ bf16x8 load_bf8(const unsigned short* p) {
    return __builtin_bit_cast(bf16x8, *reinterpret_cast<const uint4*>(p));
}
// raw HW transcendentals (v_exp_f32 = 2^x, v_log_f32 = log2)
__device__ __forceinline__ float exp2_hw(float x) {
    float r; asm("v_exp_f32 %0, %1" : "=v"(r) : "v"(x)); return r;
}
__device__ __forceinline__ float log2_hw(float x) {
    float r; asm("v_log_f32 %0, %1" : "=v"(r) : "v"(x)); return r;
}

// graph-affine XCD swizzle: node-group gi -> node0, graph g lands on XCD g%8
__device__ __forceinline__ int swz_node0(int gi, int S, int G) {
    if ((G & 7) == 0 && (S & 7) == 0) {
        int xcd = gi & 7, i = gi >> 3;
        int bpg = S >> 3;
        int gr = i / bpg, li = i - gr * bpg;
        return (xcd + 8 * gr) * S + li * 8;
    }
    return gi * 8;
}

// x[n][d] = emb[z[n]][d]; also emit bf16 hi/lo split. float4 per thread.
__global__ __launch_bounds__(256) void k_embed(const int* __restrict__ z,
        const float* __restrict__ emb, float* __restrict__ x,
        unsigned short* __restrict__ xh, unsigned short* __restrict__ xl, int N) {
    int idx = blockIdx.x * blockDim.x + threadIdx.x;       // N*32 threads
    if (idx >= N * 32) return;
    int n = idx >> 5;
    int d0 = (idx & 31) * 4;
    f4 v = *reinterpret_cast<const f4*>(emb + (size_t)z[n] * D + d0);
    *reinterpret_cast<f4*>(x + (size_t)n * D + d0) = v;
    u16x4 h, l;
    #pragma unroll
    for (int c = 0; c < 4; c++) {
        h[c] = f2bf(v[c]);
        l[c] = f2bf(v[c] - bf2f(h[c]));
    }
    *reinterpret_cast<u16x4*>(xh + (size_t)n * D + d0) = h;
    *reinterpret_cast<u16x4*>(xl + (size_t)n * D + d0) = l;
}

// jd[e] = (row[e], bits(||pos[row]-pos[col]||)) packed
__global__ void k_dist(const int* __restrict__ row, const int* __restrict__ col,
                       const float* __restrict__ pos, int2* __restrict__ jd, int E) {
    int e = blockIdx.x * blockDim.x + threadIdx.x;
    if (e >= E) return;
    int r = row[e], c = col[e];
    float dx = pos[3 * r + 0] - pos[3 * c + 0];
    float dy = pos[3 * r + 1] - pos[3 * c + 1];
    float dz = pos[3 * r + 2] - pos[3 * c + 2];
    float dist = sqrtf(dx * dx + dy * dy + dz * dz);
    jd[e] = make_int2(r, __float_as_int(dist));
}

// Pre-transpose + bf16 hi/lo split all layer weights, PRE-SCALED for base-2 gate:
// f-path (mats 0,1) x (-log2e), s-path (mats 2,3) x (+log2e).
__global__ void k_cvtW(const float* __restrict__ Wf, const float* __restrict__ Ws,
                       unsigned short* __restrict__ Wth, unsigned short* __restrict__ Wtl,
                       int L) {
    int idx = blockIdx.x * blockDim.x + threadIdx.x;
    if (idx >= L * 4 * D * D) return;
    int k = idx & 127;
    int n = (idx >> 7) & 127;
    int mat = (idx >> 14) & 3;
    int l = idx >> 16;
    const float* src = (mat < 2) ? Wf : Ws;
    float scale = (mat < 2) ? -LOG2E : LOG2E;
    float v = scale * src[(size_t)l * 257 * D + (size_t)((mat & 1) * D + k) * D + n];
    unsigned short h = f2bf(v);
    Wth[idx] = h;
    Wtl[idx] = f2bf(v - bf2f(h));
}

// Split-bf16 MFMA GEMM, A-SHARED: each block computes its 128-row tile for a
// PAIR of matrices (y=0: {Af,Bf}, y=1: {As,Bs}), loading Xh/Xl fragments once.
// Outputs interleaved: AfAs[N][256] = [Af|As], BfBs[N][256] = [Bf|Bs]  (pre-scaled)
__global__ __launch_bounds__(256) void k_gemm_mfma(
        const unsigned short* __restrict__ Xh, const unsigned short* __restrict__ Xl,
        const unsigned short* __restrict__ Wth, const unsigned short* __restrict__ Wtl,
        const float* __restrict__ bfl, const float* __restrict__ bsl,
        float* __restrict__ AfAs, float* __restrict__ BfBs, int S, int G) {
    int pair = blockIdx.y;                     // 0: mats {0,1}  1: mats {2,3}
    float* O0 = AfAs + (pair ? 128 : 0);       // mat 2p   (x_i side, has bias)
    float* O1 = BfBs + (pair ? 128 : 0);       // mat 2p+1 (x_j side)
    const float* bias = pair ? bsl : bfl;
    float bsc = pair ? LOG2E : -LOG2E;
    const unsigned short* W0 = Wth + (size_t)(2 * pair) * D * D;
    const unsigned short* W1 = Wth + (size_t)(2 * pair + 1) * D * D;

    int wave = threadIdx.x >> 6;
    int lane = threadIdx.x & 63;
    int r16 = lane & 15;
    int kg = lane >> 4;

    int xb = blockIdx.x;
    int tile0;
    if ((G & 7) == 0 && (S & 127) == 0) {
        int xcd = xb & 7, i = xb >> 3;
        int tpg = S >> 7;                       // 128-row tiles per graph
        int gi = i / tpg, t = i - gi * tpg;
        tile0 = (xcd + 8 * gi) * S + t * 128;   // graph g on XCD g%8
    } else tile0 = xb * 128;
    int row0 = tile0 + (wave >> 1) * 64;
    int wc = (wave & 1) * 64;

    f32x4 acc0[4][4], acc1[4][4];
    #pragma unroll
    for (int m = 0; m < 4; m++)
        #pragma unroll
        for (int n = 0; n < 4; n++) {
            acc0[m][n] = (f32x4){0.f, 0.f, 0.f, 0.f};
            acc1[m][n] = (f32x4){0.f, 0.f, 0.f, 0.f};
        }

    #pragma unroll
    for (int ks = 0; ks < 4; ++ks) {
        int k0 = ks * 32 + kg * 8;
        bf16x8 ah[4], al[4], b0[4], b1[4];
        #pragma unroll
        for (int m = 0; m < 4; m++) {
            size_t off = (size_t)(row0 + m * 16 + r16) * D + k0;
            ah[m] = load_bf8(Xh + off);
            al[m] = load_bf8(Xl + off);
        }
        #pragma unroll
        for (int n = 0; n < 4; n++) {
            size_t off = (size_t)(wc + n * 16 + r16) * D + k0;
            b0[n] = load_bf8(W0 + off);
            b1[n] = load_bf8(W1 + off);
        }
        #pragma unroll
        for (int m = 0; m < 4; m++)
            #pragma unroll
            for (int n = 0; n < 4; n++) {
                acc0[m][n] = __builtin_amdgcn_mfma_f32_16x16x32_bf16(ah[m], b0[n], acc0[m][n], 0, 0, 0);
                acc0[m][n] = __builtin_amdgcn_mfma_f32_16x16x32_bf16(al[m], b0[n], acc0[m][n], 0, 0, 0);
                acc1[m][n] = __builtin_amdgcn_mfma_f32_16x16x32_bf16(ah[m], b1[n], acc1[m][n], 0, 0, 0);
                acc1[m][n] = __builtin_amdgcn_mfma_f32_16x16x32_bf16(al[m], b1[n], acc1[m][n], 0, 0, 0);
            }
    }

    // C/D layout: col = lane&15, row = (lane>>4)*4 + reg
    #pragma unroll
    for (int n = 0; n < 4; n++) {
        int col = wc + n * 16 + r16;
        float bv = bias[col] * bsc;
        #pragma unroll
        for (int m = 0; m < 4; m++) {
            int rbase = row0 + m * 16 + kg * 4;
            #pragma unroll
            for (int r = 0; r < 4; r++) {
                O0[(size_t)(rbase + r) * 256 + col] = acc0[m][n][r] + bv;
                O1[(size_t)(rbase + r) * 256 + col] = acc1[m][n][r];
            }
        }
    }
}

// Edge gate + aggregate + fused 5-way stats (agg, agg^2, x, x^2, agg*x).
// 8 nodes/block, 32 lanes/node, float4/lane; graph-affine XCD swizzle.
// st slot layout per block-group (b&7 == XCD under swizzle): 640 floats =
//   [sum_agg(128) | sum_agg2(128) | sum_x(128) | sum_x2(128) | sum_aggx(128)]
__global__ __launch_bounds__(256) void k_edges(
        const int2* __restrict__ jd,
        const float* __restrict__ AfAs, const float* __restrict__ BfBs,
        const float* __restrict__ wfd, const float* __restrict__ wsd,
        const float* __restrict__ x,
        float* __restrict__ agg, float* __restrict__ st, int N, int S, int G, int deg) {
    __shared__ int2 jds[512];
    __shared__ f4 sred[256];
    __shared__ f4 sredq[256];
    int b = blockIdx.x;
    int node0 = swz_node0(b, S, G);
    int tid = threadIdx.x;
    int grp = tid >> 5, lane = tid & 31;
    bool use_lds = (8 * deg) <= 512;
    if (use_lds) {
        int tot = 8 * deg;
        int lim = (node0 + 8 <= N) ? tot : (N > node0 ? (N - node0) * deg : 0);
        for (int t = tid; t < lim; t += 256) jds[t] = jd[(size_t)node0 * deg + t];
    }
    __syncthreads();
    int node = node0 + grp;
    bool active = node < N;
    int d0 = lane * 4;
    f4 acc = {0.f, 0.f, 0.f, 0.f};
    f4 xv = {0.f, 0.f, 0.f, 0.f};
    if (active) {
        const f4 af4 = *reinterpret_cast<const f4*>(AfAs + (size_t)node * 256 + d0);
        const f4 as4 = *reinterpret_cast<const f4*>(AfAs + (size_t)node * 256 + 128 + d0);
        const f4 wf4 = *reinterpret_cast<const f4*>(wfd + d0) * (-LOG2E);
        const f4 ws4 = *reinterpret_cast<const f4*>(wsd + d0) * (LOG2E);
        const int2* jrow = use_lds ? (jds + grp * deg) : (jd + (size_t)node * deg);
        #pragma unroll 8
        for (int e = 0; e < deg; e++) {
            int2 p = jrow[e];
            float dst = __int_as_float(p.y);
            int off = (p.x << 8) + d0;          // 32-bit offset
            f4 bf4 = *reinterpret_cast<const f4*>(BfBs + off);
            f4 bs4 = *reinterpret_cast<const f4*>(BfBs + off + 128);
            #pragma unroll
            for (int c = 0; c < 4; c++) {
                float u2 = fmaf(dst, wf4[c], af4[c]) + bf4[c];   // -log2e*u
                float v2 = fmaf(dst, ws4[c], as4[c]) + bs4[c];   // +log2e*v
                float sE = exp2_hw(u2);
                float tE = exp2_hw(v2);
                float sg = __builtin_amdgcn_rcpf(1.0f + sE);     // sigmoid(u)
                float sp = log2_hw(1.0f + tE);                   // softplus(v)/ln2
                acc[c] = fmaf(sg, sp, acc[c]);
            }
        }
        *reinterpret_cast<f4*>(agg + (size_t)node * D + d0) = acc;
        xv = *reinterpret_cast<const f4*>(x + (size_t)node * D + d0);
    }
    float* stb = st + (b & 7) * 640;
    // round 1: sum_agg, sum_agg2
    sred[tid] = acc;
    sredq[tid] = acc * acc;
    __syncthreads();
    if (tid < 64) {
        int which = tid >> 5, l = tid & 31;
        f4 s = which ? sredq[l] : sred[l];
        #pragma unroll
        for (int g = 1; g < 8; g++) s += which ? sredq[g * 32 + l] : sred[g * 32 + l];
        float* dstp = stb + which * 128;
        #pragma unroll
        for (int c = 0; c < 4; c++) atomicAdd(dstp + l * 4 + c, s[c]);
    }
    __syncthreads();
    // round 2: sum_x, sum_x2
    sred[tid] = xv;
    sredq[tid] = xv * xv;
    __syncthreads();
    if (tid < 64) {
        int which = tid >> 5, l = tid & 31;
        f4 s = which ? sredq[l] : sred[l];
        #pragma unroll
        for (int g = 1; g < 8; g++) s += which ? sredq[g * 32 + l] : sred[g * 32 + l];
        float* dstp = stb + 256 + which * 128;
        #pragma unroll
        for (int c = 0; c < 4; c++) atomicAdd(dstp + l * 4 + c, s[c]);
    }
    __syncthreads();
    // round 3: sum_agg*x
    sred[tid] = acc * xv;
    __syncthreads();
    if (tid < 32) {
        f4 s = sred[tid];
        #pragma unroll
        for (int g = 1; g < 8; g++) s += sred[g * 32 + tid];
        #pragma unroll
        for (int c = 0; c < 4; c++) atomicAdd(stb + 512 + tid * 4 + c, s[c]);
    }
}

// Fused BN1+residual+BN2+ReLU, stats2 computed ALGEBRAICALLY:
//   xn = A*agg + C + x,  A = gc*inv1, C = bc - A*mu1
//   mu2 = bc + mean(x)   (A-terms cancel exactly)
//   E[xn^2] = (A^2*Sagg2 + 2AC*Sagg + 2A*Saggx + 2C*Sx + Sx2)/N + C^2
// One pass: read agg + x, write x, xh, xl.  NG blocks, 8 nodes/block, swizzled.
__global__ __launch_bounds__(256) void k_bnfused(
        const float* __restrict__ st,
        const float* __restrict__ gc, const float* __restrict__ bc,
        const float* __restrict__ gn, const float* __restrict__ bnb,
        const float* __restrict__ agg, float* __restrict__ x,
        unsigned short* __restrict__ xh, unsigned short* __restrict__ xl,
        int N, int S, int G) {
    int tid = threadIdx.x;
    int lane = tid & 31, grp = tid >> 5;
    int d0 = lane * 4;
    int node = swz_node0(blockIdx.x, S, G) + grp;
    if (node >= N) return;
    float invN = 1.0f / (float)N;
    f4 Sa = {0.f, 0.f, 0.f, 0.f}, Sa2 = {0.f, 0.f, 0.f, 0.f};
    f4 Sx = {0.f, 0.f, 0.f, 0.f}, Sx2 = {0.f, 0.f, 0.f, 0.f}, Sax = {0.f, 0.f, 0.f, 0.f};
    #pragma unroll
    for (int r = 0; r < 8; r++) {
        const float* stb = st + r * 640;
        Sa  += *reinterpret_cast<const f4*>(stb + d0);
        Sa2 += *reinterpret_cast<const f4*>(stb + 128 + d0);
        Sx  += *reinterpret_cast<const f4*>(stb + 256 + d0);
        Sx2 += *reinterpret_cast<const f4*>(stb + 384 + d0);
        Sax += *reinterpret_cast<const f4*>(stb + 512 + d0);
    }
    f4 g1 = *reinterpret_cast<const f4*>(gc + d0);
    f4 b1v = *reinterpret_cast<const f4*>(bc + d0);
    f4 g2 = *reinterpret_cast<const f4*>(gn + d0);
    f4 b2v = *reinterpret_cast<const f4*>(bnb + d0);
    f4 A, C, mu2, inv2;
    #pragma unroll
    for (int c = 0; c < 4; c++) {
        float m1 = Sa[c] * invN;
        float var1 = Sa2[c] * invN - m1 * m1;
        float i1 = rsqrtf(var1 + 1e-5f);
        float a = g1[c] * i1;
        float cc = b1v[c] - a * m1;
        float mx = Sx[c] * invN;
        float m2 = b1v[c] + mx;
        float e2 = (a * a * Sa2[c] + 2.f * a * cc * Sa[c] + 2.f * a * Sax[c]
                    + 2.f * cc * Sx[c] + Sx2[c]) * invN + cc * cc;
        float var2 = e2 - m2 * m2;
        A[c] = a; C[c] = cc; mu2[c] = m2;
        inv2[c] = rsqrtf(var2 + 1e-5f);
    }
    size_t idx = (size_t)node * D + d0;
    f4 av = *reinterpret_cast<const f4*>(agg + idx);
    f4 xv = *reinterpret_cast<const f4*>(x + idx);
    f4 o;
    u16x4 h, l;
    #pragma unroll
    for (int c = 0; c < 4; c++) {
        float xn = fmaf(A[c], av[c], C[c]) + xv[c];
        float t = fmaf(g2[c] * (xn - mu2[c]), inv2[c], b2v[c]);
        t = fmaxf(t, 0.0f);
        o[c] = t;
        h[c] = f2bf(t);
        l[c] = f2bf(t - bf2f(h[c]));
    }
    *reinterpret_cast<f4*>(x + idx) = o;
    *reinterpret_cast<u16x4*>(xh + idx) = h;
    *reinterpret_cast<u16x4*>(xl + idx) = l;
}

// Per-graph feature sums: 8 blocks per graph (g = b&31 so XCD matches g%8)
__global__ __launch_bounds__(256) void k_pool(const float* __restrict__ x,
        float* __restrict__ gsum, int S, int G) {
    __shared__ f4 s[256];
    int b = blockIdx.x;
    int g, sub;
    if ((G & 31) == 0) { g = b & 31; sub = b >> 5; }
    else               { g = b >> 3; sub = b & 7; }
    int tid = threadIdx.x;
    int grp = tid >> 5, lane = tid & 31;
    int d0 = lane * 4;
    f4 a = {0.f, 0.f, 0.f, 0.f};
    for (int r = sub * 8 + grp; r < S; r += 64)
        a += *reinterpret_cast<const f4*>(x + ((size_t)g * S + r) * D + d0);
    s[tid] = a;
    __syncthreads();
    if (tid < 32) {
        f4 acc = s[tid];
        #pragma unroll
        for (int q = 1; q < 8; q++) acc += s[q * 32 + tid];
        #pragma unroll
        for (int c = 0; c < 4; c++) atomicAdd(&gsum[g * D + tid * 4 + c], acc[c]);
    }
}

// out[g] = relu(gmean@W1+b1) @ W2 + b2
__global__ __launch_bounds__(128) void k_mlp(const float* __restrict__ gsum,
        const float* __restrict__ W1, const float* __restrict__ b1,
        const float* __restrict__ W2, const float* __restrict__ b2,
        float* __restrict__ out, int S) {
    __shared__ float gm[D];
    __shared__ float red[128];
    int g = blockIdx.x, d = threadIdx.x;
    gm[d] = gsum[g * D + d] / (float)S;
    __syncthreads();
    float h = b1[d];
    #pragma unroll 8
    for (int k = 0; k < D; k++) h = fmaf(gm[k], W1[k * D + d], h);
    h = fmaxf(h, 0.0f);
    red[d] = h * W2[d];
    __syncthreads();
    for (int st = 64; st > 0; st >>= 1) {
        if (d < st) red[d] += red[d + st];
        __syncthreads();
    }
    if (d == 0) out[g] = red[0] + b2[0];
}

extern "C" void kernel_launch(void* const* d_in, const int* in_sizes, int n_in,
                              void* d_out, int out_size, void* d_ws, size_t ws_size,
                              hipStream_t stream) {
    const int*   z    = (const int*)d_in[0];
    const float* pos  = (const float*)d_in[1];
    const int*   eidx = (const int*)d_in[3];
    const float* emb  = (const float*)d_in[4];
    const float* Wf   = (const float*)d_in[5];
    const float* bf   = (const float*)d_in[6];
    const float* Ws   = (const float*)d_in[7];
    const float* bs   = (const float*)d_in[8];
    const float* gc   = (const float*)d_in[9];
    const float* bc   = (const float*)d_in[10];
    const float* gn   = (const float*)d_in[11];
    const float* bnb  = (const float*)d_in[12];
    const float* W1   = (const float*)d_in[13];
    const float* b1   = (const float*)d_in[14];
    const float* W2   = (const float*)d_in[15];
    const float* b2   = (const float*)d_in[16];

    int N = in_sizes[0];
    int E = in_sizes[3] / 2;
    int L = in_sizes[6] / D;
    int deg = E / N;
    int G = out_size;
    int S = N / G;

    const int* row = eidx;
    const int* col = eidx + E;

    float* ws = (float*)d_ws;
    size_t nd = (size_t)N * D;
    float* x    = ws;                  // [N][128]
    float* AfAs = x + nd;              // [N][256]
    float* BfBs = AfAs + 2 * nd;       // [N][256]
    float* agg  = BfBs + 2 * nd;       // [N][128]
    int2*  jd   = (int2*)(agg + nd);   // [E] packed (j, dist)
    unsigned short* xh  = (unsigned short*)(jd + E);
    unsigned short* xl  = xh + nd;
    unsigned short* Wth = xl + nd;                          // L*4*128*128 bf16
    unsigned short* Wtl = Wth + (size_t)L * 4 * D * D;
    float* stats = (float*)(Wtl + (size_t)L * 4 * D * D);   // L * 8*640 floats
    float* gsum  = stats + (size_t)L * 5120;                // G*128 floats

    hipMemsetAsync(stats, 0, ((size_t)L * 5120 + (size_t)G * D) * sizeof(float), stream);

    k_cvtW<<<(L * 4 * D * D + 255) / 256, 256, 0, stream>>>(Wf, Ws, Wth, Wtl, L);
    k_embed<<<(N * 32 + 255) / 256, 256, 0, stream>>>(z, emb, x, xh, xl, N);
    k_dist<<<(E + 255) / 256, 256, 0, stream>>>(row, col, pos, jd, E);

    int NG = (N + 7) / 8;
    for (int l = 0; l < L; ++l) {
        const float* Wfl = Wf + (size_t)l * 257 * D;
        const float* Wsl = Ws + (size_t)l * 257 * D;
        float* stp = stats + (size_t)l * 5120;
        k_gemm_mfma<<<dim3(N / 128, 2), 256, 0, stream>>>(
            xh, xl, Wth + (size_t)l * 4 * D * D, Wtl + (size_t)l * 4 * D * D,
            bf + l * D, bs + l * D, AfAs, BfBs, S, G);
        k_edges<<<NG, 256, 0, stream>>>(jd, AfAs, BfBs, Wfl + 256 * D, Wsl + 256 * D,
                                        x, agg, stp, N, S, G, deg);
        k_bnfused<<<NG, 256, 0, stream>>>(stp, gc + l * D, bc + l * D,
                                          gn + l * D, bnb + l * D,
                                          agg, x, xh, xl, N, S, G);
    }
    k_pool<<<G * 8, 256, 0, stream>>>(x, gsum, S, G);
    k_mlp<<<G, 128, 0, stream>>>(gsum, W1, b1, W2, b2, (float*)d_out, S);
}

// Round 13
// 547.068 us; speedup vs baseline: 3.0198x; 1.0062x over previous
//
#include <hip/hip_runtime.h>
#include <math.h>

#define D 128
#define LOG2E 1.44269504f

typedef short bf16x8 __attribute__((ext_vector_type(8)));
typedef float f32x4 __attribute__((ext_vector_type(4)));
typedef float f4 __attribute__((ext_vector_type(4)));
typedef float f2v __attribute__((ext_vector_type(2)));
typedef unsigned short u16x4 __attribute__((ext_vector_type(4)));

__device__ __forceinline__ unsigned short f2bf(float f) {
    unsigned int u = __float_as_uint(f);
    u += 0x7fff + ((u >> 16) & 1);   // round-to-nearest-even
    return (unsigned short)(u >> 16);
}
__device__ __forceinline__ float bf2f(unsigned short h) {
    return __uint_as_float(((unsigned int)h) << 16);
}
__device__ __forceinline__ bf16x8 load_bf8(const unsigned short* p) {
    return __builtin_bit_cast(bf16x8, *reinterpret_cast<const uint4*>(p));
}
// raw HW transcendentals (v_exp_f32 = 2^x, v_log_f32 = log2)
__device__ __forceinline__ float exp2_hw(float x) {
    float r; asm("v_exp_f32 %0, %1" : "=v"(r) : "v"(x)); return r;
}
__device__ __forceinline__ float log2_hw(float x) {
    float r; asm("v_log_f32 %0, %1" : "=v"(r) : "v"(x)); return r;
}

// graph-affine XCD swizzle: node-group gi -> node0, graph g lands on XCD g%8
__device__ __forceinline__ int swz_node0(int gi, int S, int G) {
    if ((G & 7) == 0 && (S & 7) == 0) {
        int xcd = gi & 7, i = gi >> 3;
        int bpg = S >> 3;
        int gr = i / bpg, li = i - gr * bpg;
        return (xcd + 8 * gr) * S + li * 8;
    }
    return gi * 8;
}

// Merged startup: embed | dist | cvtW, partitioned by blockIdx range.
// jd[e] = (row[e]*256, bits(dist))  -- index pre-scaled for k_edges.
__global__ __launch_bounds__(256) void k_setup(
        const int* __restrict__ z, const float* __restrict__ emb,
        float* __restrict__ x, unsigned short* __restrict__ xh,
        unsigned short* __restrict__ xl,
        const int* __restrict__ row, const int* __restrict__ col,
        const float* __restrict__ pos, int2* __restrict__ jd,
        const float* __restrict__ Wf, const float* __restrict__ Ws,
        unsigned short* __restrict__ Wth, unsigned short* __restrict__ Wtl,
        int N, int E, int L, int nb_embed, int nb_dist) {
    int b = blockIdx.x;
    if (b < nb_embed) {
        int idx = b * 256 + threadIdx.x;                 // N*32 threads
        if (idx >= N * 32) return;
        int n = idx >> 5;
        int d0 = (idx & 31) * 4;
        f4 v = *reinterpret_cast<const f4*>(emb + (size_t)z[n] * D + d0);
        *reinterpret_cast<f4*>(x + (size_t)n * D + d0) = v;
        u16x4 h, l;
        #pragma unroll
        for (int c = 0; c < 4; c++) {
            h[c] = f2bf(v[c]);
            l[c] = f2bf(v[c] - bf2f(h[c]));
        }
        *reinterpret_cast<u16x4*>(xh + (size_t)n * D + d0) = h;
        *reinterpret_cast<u16x4*>(xl + (size_t)n * D + d0) = l;
    } else if (b < nb_embed + nb_dist) {
        int e = (b - nb_embed) * 256 + threadIdx.x;
        if (e >= E) return;
        int r = row[e], c = col[e];
        float dx = pos[3 * r + 0] - pos[3 * c + 0];
        float dy = pos[3 * r + 1] - pos[3 * c + 1];
        float dz = pos[3 * r + 2] - pos[3 * c + 2];
        float dist = sqrtf(dx * dx + dy * dy + dz * dz);
        jd[e] = make_int2(r * 256, __float_as_int(dist));   // pre-scaled index
    } else {
        int idx = (b - nb_embed - nb_dist) * 256 + threadIdx.x;
        if (idx >= L * 4 * D * D) return;
        int k = idx & 127;
        int n = (idx >> 7) & 127;
        int mat = (idx >> 14) & 3;
        int l = idx >> 16;
        const float* src = (mat < 2) ? Wf : Ws;
        float scale = (mat < 2) ? -LOG2E : LOG2E;
        float v = scale * src[(size_t)l * 257 * D + (size_t)((mat & 1) * D + k) * D + n];
        unsigned short h = f2bf(v);
        Wth[idx] = h;
        Wtl[idx] = f2bf(v - bf2f(h));
    }
}

// Split-bf16 MFMA GEMM, A-SHARED: each block computes its 128-row tile for a
// PAIR of matrices (y=0: {Af,Bf}, y=1: {As,Bs}), loading Xh/Xl fragments once.
// Outputs interleaved: AfAs[N][256] = [Af|As], BfBs[N][256] = [Bf|Bs]  (pre-scaled)
__global__ __launch_bounds__(256) void k_gemm_mfma(
        const unsigned short* __restrict__ Xh, const unsigned short* __restrict__ Xl,
        const unsigned short* __restrict__ Wth, const unsigned short* __restrict__ Wtl,
        const float* __restrict__ bfl, const float* __restrict__ bsl,
        float* __restrict__ AfAs, float* __restrict__ BfBs, int S, int G) {
    int pair = blockIdx.y;                     // 0: mats {0,1}  1: mats {2,3}
    float* O0 = AfAs + (pair ? 128 : 0);       // mat 2p   (x_i side, has bias)
    float* O1 = BfBs + (pair ? 128 : 0);       // mat 2p+1 (x_j side)
    const float* bias = pair ? bsl : bfl;
    float bsc = pair ? LOG2E : -LOG2E;
    const unsigned short* W0 = Wth + (size_t)(2 * pair) * D * D;
    const unsigned short* W1 = Wth + (size_t)(2 * pair + 1) * D * D;

    int wave = threadIdx.x >> 6;
    int lane = threadIdx.x & 63;
    int r16 = lane & 15;
    int kg = lane >> 4;

    int xb = blockIdx.x;
    int tile0;
    if ((G & 7) == 0 && (S & 127) == 0) {
        int xcd = xb & 7, i = xb >> 3;
        int tpg = S >> 7;                       // 128-row tiles per graph
        int gi = i / tpg, t = i - gi * tpg;
        tile0 = (xcd + 8 * gi) * S + t * 128;   // graph g on XCD g%8
    } else tile0 = xb * 128;
    int row0 = tile0 + (wave >> 1) * 64;
    int wc = (wave & 1) * 64;

    f32x4 acc0[4][4], acc1[4][4];
    #pragma unroll
    for (int m = 0; m < 4; m++)
        #pragma unroll
        for (int n = 0; n < 4; n++) {
            acc0[m][n] = (f32x4){0.f, 0.f, 0.f, 0.f};
            acc1[m][n] = (f32x4){0.f, 0.f, 0.f, 0.f};
        }

    #pragma unroll
    for (int ks = 0; ks < 4; ++ks) {
        int k0 = ks * 32 + kg * 8;
        bf16x8 ah[4], al[4], b0[4], b1[4];
        #pragma unroll
        for (int m = 0; m < 4; m++) {
            size_t off = (size_t)(row0 + m * 16 + r16) * D + k0;
            ah[m] = load_bf8(Xh + off);
            al[m] = load_bf8(Xl + off);
        }
        #pragma unroll
        for (int n = 0; n < 4; n++) {
            size_t off = (size_t)(wc + n * 16 + r16) * D + k0;
            b0[n] = load_bf8(W0 + off);
            b1[n] = load_bf8(W1 + off);
        }
        #pragma unroll
        for (int m = 0; m < 4; m++)
            #pragma unroll
            for (int n = 0; n < 4; n++) {
                acc0[m][n] = __builtin_amdgcn_mfma_f32_16x16x32_bf16(ah[m], b0[n], acc0[m][n], 0, 0, 0);
                acc0[m][n] = __builtin_amdgcn_mfma_f32_16x16x32_bf16(al[m], b0[n], acc0[m][n], 0, 0, 0);
                acc1[m][n] = __builtin_amdgcn_mfma_f32_16x16x32_bf16(ah[m], b1[n], acc1[m][n], 0, 0, 0);
                acc1[m][n] = __builtin_amdgcn_mfma_f32_16x16x32_bf16(al[m], b1[n], acc1[m][n], 0, 0, 0);
            }
    }

    // C/D layout: col = lane&15, row = (lane>>4)*4 + reg
    #pragma unroll
    for (int n = 0; n < 4; n++) {
        int col = wc + n * 16 + r16;
        float bv = bias[col] * bsc;
        #pragma unroll
        for (int m = 0; m < 4; m++) {
            int rbase = row0 + m * 16 + kg * 4;
            #pragma unroll
            for (int r = 0; r < 4; r++) {
                O0[(size_t)(rbase + r) * 256 + col] = acc0[m][n][r] + bv;
                O1[(size_t)(rbase + r) * 256 + col] = acc1[m][n][r];
            }
        }
    }
}

// Edge gate + aggregate + fused 5-way stats (agg, agg^2, x, x^2, agg*x).
// 8 nodes/block, 32 lanes/node, float4/lane; graph-affine XCD swizzle.
// Affine math written as float2 vector ops -> compiler may select v_pk_fma_f32 /
// v_pk_add_f32 (VOP3P), cutting 4 affine insts/channel to 2. Identical fp32 values.
// st slot layout per block-group (b&7 == XCD under swizzle): 640 floats =
//   [sum_agg(128) | sum_agg2(128) | sum_x(128) | sum_x2(128) | sum_aggx(128)]
__global__ __launch_bounds__(256) void k_edges(
        const int2* __restrict__ jd,
        const float* __restrict__ AfAs, const float* __restrict__ BfBs,
        const float* __restrict__ wfd, const float* __restrict__ wsd,
        const float* __restrict__ x,
        float* __restrict__ agg, float* __restrict__ st, int N, int S, int G, int deg) {
    __shared__ int2 jds[512];
    __shared__ f4 sred[256];
    __shared__ f4 sredq[256];
    int b = blockIdx.x;
    int node0 = swz_node0(b, S, G);
    int tid = threadIdx.x;
    int grp = tid >> 5, lane = tid & 31;
    bool use_lds = (8 * deg) <= 512;
    if (use_lds) {
        int tot = 8 * deg;
        int lim = (node0 + 8 <= N) ? tot : (N > node0 ? (N - node0) * deg : 0);
        for (int t = tid; t < lim; t += 256) jds[t] = jd[(size_t)node0 * deg + t];
    }
    __syncthreads();
    int node = node0 + grp;
    bool active = node < N;
    int d0 = lane * 4;
    f4 acc = {0.f, 0.f, 0.f, 0.f};
    f4 xv = {0.f, 0.f, 0.f, 0.f};
    if (active) {
        const f4 af4 = *reinterpret_cast<const f4*>(AfAs + (size_t)node * 256 + d0);
        const f4 as4 = *reinterpret_cast<const f4*>(AfAs + (size_t)node * 256 + 128 + d0);
        const f4 wf4 = *reinterpret_cast<const f4*>(wfd + d0) * (-LOG2E);
        const f4 ws4 = *reinterpret_cast<const f4*>(wsd + d0) * (LOG2E);
        f2v af01 = __builtin_shufflevector(af4, af4, 0, 1);
        f2v af23 = __builtin_shufflevector(af4, af4, 2, 3);
        f2v as01 = __builtin_shufflevector(as4, as4, 0, 1);
        f2v as23 = __builtin_shufflevector(as4, as4, 2, 3);
        f2v wf01 = __builtin_shufflevector(wf4, wf4, 0, 1);
        f2v wf23 = __builtin_shufflevector(wf4, wf4, 2, 3);
        f2v ws01 = __builtin_shufflevector(ws4, ws4, 0, 1);
        f2v ws23 = __builtin_shufflevector(ws4, ws4, 2, 3);
        const int2* jrow = use_lds ? (jds + grp * deg) : (jd + (size_t)node * deg);
        #pragma unroll 8
        for (int e = 0; e < deg; e++) {
            int2 p = jrow[e];
            float dst = __int_as_float(p.y);
            int off = p.x + d0;                 // p.x pre-scaled by 256 in k_setup
            f4 bf4 = *reinterpret_cast<const f4*>(BfBs + off);
            f4 bs4 = *reinterpret_cast<const f4*>(BfBs + off + 128);
            f2v dst2 = {dst, dst};
            f2v u01 = dst2 * wf01 + af01 + __builtin_shufflevector(bf4, bf4, 0, 1);
            f2v u23 = dst2 * wf23 + af23 + __builtin_shufflevector(bf4, bf4, 2, 3);
            f2v v01 = dst2 * ws01 + as01 + __builtin_shufflevector(bs4, bs4, 0, 1);
            f2v v23 = dst2 * ws23 + as23 + __builtin_shufflevector(bs4, bs4, 2, 3);
            float u[4] = {u01[0], u01[1], u23[0], u23[1]};
            float v[4] = {v01[0], v01[1], v23[0], v23[1]};
            #pragma unroll
            for (int c = 0; c < 4; c++) {
                float sE = exp2_hw(u[c]);                        // 2^(-log2e*u) = e^{-u}
                float tE = exp2_hw(v[c]);                        // e^{v}
                float sg = __builtin_amdgcn_rcpf(1.0f + sE);     // sigmoid(u)
                float sp = log2_hw(1.0f + tE);                   // softplus(v)/ln2
                acc[c] = fmaf(sg, sp, acc[c]);
            }
        }
        *reinterpret_cast<f4*>(agg + (size_t)node * D + d0) = acc;
        xv = *reinterpret_cast<const f4*>(x + (size_t)node * D + d0);
    }
    float* stb = st + (b & 7) * 640;
    // round 1: sum_agg, sum_agg2
    sred[tid] = acc;
    sredq[tid] = acc * acc;
    __syncthreads();
    if (tid < 64) {
        int which = tid >> 5, l = tid & 31;
        f4 s = which ? sredq[l] : sred[l];
        #pragma unroll
        for (int g = 1; g < 8; g++) s += which ? sredq[g * 32 + l] : sred[g * 32 + l];
        float* dstp = stb + which * 128;
        #pragma unroll
        for (int c = 0; c < 4; c++) atomicAdd(dstp + l * 4 + c, s[c]);
    }
    __syncthreads();
    // round 2: sum_x, sum_x2
    sred[tid] = xv;
    sredq[tid] = xv * xv;
    __syncthreads();
    if (tid < 64) {
        int which = tid >> 5, l = tid & 31;
        f4 s = which ? sredq[l] : sred[l];
        #pragma unroll
        for (int g = 1; g < 8; g++) s += which ? sredq[g * 32 + l] : sred[g * 32 + l];
        float* dstp = stb + 256 + which * 128;
        #pragma unroll
        for (int c = 0; c < 4; c++) atomicAdd(dstp + l * 4 + c, s[c]);
    }
    __syncthreads();
    // round 3: sum_agg*x
    sred[tid] = acc * xv;
    __syncthreads();
    if (tid < 32) {
        f4 s = sred[tid];
        #pragma unroll
        for (int g = 1; g < 8; g++) s += sred[g * 32 + tid];
        #pragma unroll
        for (int c = 0; c < 4; c++) atomicAdd(stb + 512 + tid * 4 + c, s[c]);
    }
}

// Fused BN1+residual+BN2+ReLU, stats2 computed ALGEBRAICALLY:
//   xn = A*agg + C + x,  A = gc*inv1, C = bc - A*mu1
//   mu2 = bc + mean(x)   (A-terms cancel exactly)
//   E[xn^2] = (A^2*Sagg2 + 2AC*Sagg + 2A*Saggx + 2C*Sx + Sx2)/N + C^2
// One pass: read agg + x, write x, xh, xl.  NG blocks, 8 nodes/block, swizzled.
__global__ __launch_bounds__(256) void k_bnfused(
        const float* __restrict__ st,
        const float* __restrict__ gc, const float* __restrict__ bc,
        const float* __restrict__ gn, const float* __restrict__ bnb,
        const float* __restrict__ agg, float* __restrict__ x,
        unsigned short* __restrict__ xh, unsigned short* __restrict__ xl,
        int N, int S, int G) {
    int tid = threadIdx.x;
    int lane = tid & 31, grp = tid >> 5;
    int d0 = lane * 4;
    int node = swz_node0(blockIdx.x, S, G) + grp;
    if (node >= N) return;
    float invN = 1.0f / (float)N;
    f4 Sa = {0.f, 0.f, 0.f, 0.f}, Sa2 = {0.f, 0.f, 0.f, 0.f};
    f4 Sx = {0.f, 0.f, 0.f, 0.f}, Sx2 = {0.f, 0.f, 0.f, 0.f}, Sax = {0.f, 0.f, 0.f, 0.f};
    #pragma unroll
    for (int r = 0; r < 8; r++) {
        const float* stb = st + r * 640;
        Sa  += *reinterpret_cast<const f4*>(stb + d0);
        Sa2 += *reinterpret_cast<const f4*>(stb + 128 + d0);
        Sx  += *reinterpret_cast<const f4*>(stb + 256 + d0);
        Sx2 += *reinterpret_cast<const f4*>(stb + 384 + d0);
        Sax += *reinterpret_cast<const f4*>(stb + 512 + d0);
    }
    f4 g1 = *reinterpret_cast<const f4*>(gc + d0);
    f4 b1v = *reinterpret_cast<const f4*>(bc + d0);
    f4 g2 = *reinterpret_cast<const f4*>(gn + d0);
    f4 b2v = *reinterpret_cast<const f4*>(bnb + d0);
    f4 A, C, mu2, inv2;
    #pragma unroll
    for (int c = 0; c < 4; c++) {
        float m1 = Sa[c] * invN;
        float var1 = Sa2[c] * invN - m1 * m1;
        float i1 = rsqrtf(var1 + 1e-5f);
        float a = g1[c] * i1;
        float cc = b1v[c] - a * m1;
        float mx = Sx[c] * invN;
        float m2 = b1v[c] + mx;
        float e2 = (a * a * Sa2[c] + 2.f * a * cc * Sa[c] + 2.f * a * Sax[c]
                    + 2.f * cc * Sx[c] + Sx2[c]) * invN + cc * cc;
        float var2 = e2 - m2 * m2;
        A[c] = a; C[c] = cc; mu2[c] = m2;
        inv2[c] = rsqrtf(var2 + 1e-5f);
    }
    size_t idx = (size_t)node * D + d0;
    f4 av = *reinterpret_cast<const f4*>(agg + idx);
    f4 xv = *reinterpret_cast<const f4*>(x + idx);
    f4 o;
    u16x4 h, l;
    #pragma unroll
    for (int c = 0; c < 4; c++) {
        float xn = fmaf(A[c], av[c], C[c]) + xv[c];
        float t = fmaf(g2[c] * (xn - mu2[c]), inv2[c], b2v[c]);
        t = fmaxf(t, 0.0f);
        o[c] = t;
        h[c] = f2bf(t);
        l[c] = f2bf(t - bf2f(h[c]));
    }
    *reinterpret_cast<f4*>(x + idx) = o;
    *reinterpret_cast<u16x4*>(xh + idx) = h;
    *reinterpret_cast<u16x4*>(xl + idx) = l;
}

// Per-graph feature sums: 8 blocks per graph (g = b&31 so XCD matches g%8)
__global__ __launch_bounds__(256) void k_pool(const float* __restrict__ x,
        float* __restrict__ gsum, int S, int G) {
    __shared__ f4 s[256];
    int b = blockIdx.x;
    int g, sub;
    if ((G & 31) == 0) { g = b & 31; sub = b >> 5; }
    else               { g = b >> 3; sub = b & 7; }
    int tid = threadIdx.x;
    int grp = tid >> 5, lane = tid & 31;
    int d0 = lane * 4;
    f4 a = {0.f, 0.f, 0.f, 0.f};
    for (int r = sub * 8 + grp; r < S; r += 64)
        a += *reinterpret_cast<const f4*>(x + ((size_t)g * S + r) * D + d0);
    s[tid] = a;
    __syncthreads();
    if (tid < 32) {
        f4 acc = s[tid];
        #pragma unroll
        for (int q = 1; q < 8; q++) acc += s[q * 32 + tid];
        #pragma unroll
        for (int c = 0; c < 4; c++) atomicAdd(&gsum[g * D + tid * 4 + c], acc[c]);
    }
}

// out[g] = relu(gmean@W1+b1) @ W2 + b2
__global__ __launch_bounds__(128) void k_mlp(const float* __restrict__ gsum,
        const float* __restrict__ W1, const float* __restrict__ b1,
        const float* __restrict__ W2, const float* __restrict__ b2,
        float* __restrict__ out, int S) {
    __shared__ float gm[D];
    __shared__ float red[128];
    int g = blockIdx.x, d = threadIdx.x;
    gm[d] = gsum[g * D + d] / (float)S;
    __syncthreads();
    float h = b1[d];
    #pragma unroll 8
    for (int k = 0; k < D; k++) h = fmaf(gm[k], W1[k * D + d], h);
    h = fmaxf(h, 0.0f);
    red[d] = h * W2[d];
    __syncthreads();
    for (int st = 64; st > 0; st >>= 1) {
        if (d < st) red[d] += red[d + st];
        __syncthreads();
    }
    if (d == 0) out[g] = red[0] + b2[0];
}

extern "C" void kernel_launch(void* const* d_in, const int* in_sizes, int n_in,
                              void* d_out, int out_size, void* d_ws, size_t ws_size,
                              hipStream_t stream) {
    const int*   z    = (const int*)d_in[0];
    const float* pos  = (const float*)d_in[1];
    const int*   eidx = (const int*)d_in[3];
    const float* emb  = (const float*)d_in[4];
    const float* Wf   = (const float*)d_in[5];
    const float* bf   = (const float*)d_in[6];
    const float* Ws   = (const float*)d_in[7];
    const float* bs   = (const float*)d_in[8];
    const float* gc   = (const float*)d_in[9];
    const float* bc   = (const float*)d_in[10];
    const float* gn   = (const float*)d_in[11];
    const float* bnb  = (const float*)d_in[12];
    const float* W1   = (const float*)d_in[13];
    const float* b1   = (const float*)d_in[14];
    const float* W2   = (const float*)d_in[15];
    const float* b2   = (const float*)d_in[16];

    int N = in_sizes[0];
    int E = in_sizes[3] / 2;
    int L = in_sizes[6] / D;
    int deg = E / N;
    int G = out_size;
    int S = N / G;

    const int* row = eidx;
    const int* col = eidx + E;

    float* ws = (float*)d_ws;
    size_t nd = (size_t)N * D;
    float* x    = ws;                  // [N][128]
    float* AfAs = x + nd;              // [N][256]
    float* BfBs = AfAs + 2 * nd;       // [N][256]
    float* agg  = BfBs + 2 * nd;       // [N][128]
    int2*  jd   = (int2*)(agg + nd);   // [E] packed (j*256, dist)
    unsigned short* xh  = (unsigned short*)(jd + E);
    unsigned short* xl  = xh + nd;
    unsigned short* Wth = xl + nd;                          // L*4*128*128 bf16
    unsigned short* Wtl = Wth + (size_t)L * 4 * D * D;
    float* stats = (float*)(Wtl + (size_t)L * 4 * D * D);   // L * 8*640 floats
    float* gsum  = stats + (size_t)L * 5120;                // G*128 floats

    hipMemsetAsync(stats, 0, ((size_t)L * 5120 + (size_t)G * D) * sizeof(float), stream);

    int nb_embed = (N * 32 + 255) / 256;
    int nb_dist  = (E + 255) / 256;
    int nb_cvtw  = (L * 4 * D * D + 255) / 256;
    k_setup<<<nb_embed + nb_dist + nb_cvtw, 256, 0, stream>>>(
        z, emb, x, xh, xl, row, col, pos, jd, Wf, Ws, Wth, Wtl,
        N, E, L, nb_embed, nb_dist);

    int NG = (N + 7) / 8;
    for (int l = 0; l < L; ++l) {
        const float* Wfl = Wf + (size_t)l * 257 * D;
        const float* Wsl = Ws + (size_t)l * 257 * D;
        float* stp = stats + (size_t)l * 5120;
        k_gemm_mfma<<<dim3(N / 128, 2), 256, 0, stream>>>(
            xh, xl, Wth + (size_t)l * 4 * D * D, Wtl + (size_t)l * 4 * D * D,
            bf + l * D, bs + l * D, AfAs, BfBs, S, G);
        k_edges<<<NG, 256, 0, stream>>>(jd, AfAs, BfBs, Wfl + 256 * D, Wsl + 256 * D,
                                        x, agg, stp, N, S, G, deg);
        k_bnfused<<<NG, 256, 0, stream>>>(stp, gc + l * D, bc + l * D,
                                          gn + l * D, bnb + l * D,
                                          agg, x, xh, xl, N, S, G);
    }
    k_pool<<<G * 8, 256, 0, stream>>>(x, gsum, S, G);
    k_mlp<<<G, 128, 0, stream>>>(gsum, W1, b1, W2, b2, (float*)d_out, S);
}

// Round 14
// 545.830 us; speedup vs baseline: 3.0267x; 1.0023x over previous
//
#include <hip/hip_runtime.h>
#include <math.h>

#define D 128
#define LOG2E 1.44269504f

typedef short bf16x8 __attribute__((ext_vector_type(8)));
typedef float f32x4 __attribute__((ext_vector_type(4)));
typedef float f4 __attribute__((ext_vector_type(4)));
typedef float f2v __attribute__((ext_vector_type(2)));
typedef unsigned short u16x4 __attribute__((ext_vector_type(4)));

__device__ __forceinline__ unsigned short f2bf(float f) {
    unsigned int u = __float_as_uint(f);
    u += 0x7fff + ((u >> 16) & 1);   // round-to-nearest-even
    return (unsigned short)(u >> 16);
}
__device__ __forceinline__ float bf2f(unsigned short h) {
    return __uint_as_float(((unsigned int)h) << 16);
}
__device__ __forceinline__ bf16x8 load_bf8(const unsigned short* p) {
    return __builtin_bit_cast(bf16x8, *reinterpret_cast<const uint4*>(p));
}
// raw HW transcendentals (v_exp_f32 = 2^x, v_log_f32 = log2)
__device__ __forceinline__ float exp2_hw(float x) {
    float r; asm("v_exp_f32 %0, %1" : "=v"(r) : "v"(x)); return r;
}
__device__ __forceinline__ float log2_hw(float x) {
    float r; asm("v_log_f32 %0, %1" : "=v"(r) : "v"(x)); return r;
}

// graph-affine XCD swizzle: node-group gi -> node0, graph g lands on XCD g%8
__device__ __forceinline__ int swz_node0(int gi, int S, int G) {
    if ((G & 7) == 0 && (S & 7) == 0) {
        int xcd = gi & 7, i = gi >> 3;
        int bpg = S >> 3;
        int gr = i / bpg, li = i - gr * bpg;
        return (xcd + 8 * gr) * S + li * 8;
    }
    return gi * 8;
}

// Merged startup: embed | dist | cvtW, partitioned by blockIdx range.
// jd[e] = (row[e]*256, bits(dist))  -- index pre-scaled for k_edges.
__global__ __launch_bounds__(256) void k_setup(
        const int* __restrict__ z, const float* __restrict__ emb,
        float* __restrict__ x, unsigned short* __restrict__ xh,
        unsigned short* __restrict__ xl,
        const int* __restrict__ row, const int* __restrict__ col,
        const float* __restrict__ pos, int2* __restrict__ jd,
        const float* __restrict__ Wf, const float* __restrict__ Ws,
        unsigned short* __restrict__ Wth, unsigned short* __restrict__ Wtl,
        int N, int E, int L, int nb_embed, int nb_dist) {
    int b = blockIdx.x;
    if (b < nb_embed) {
        int idx = b * 256 + threadIdx.x;                 // N*32 threads
        if (idx >= N * 32) return;
        int n = idx >> 5;
        int d0 = (idx & 31) * 4;
        f4 v = *reinterpret_cast<const f4*>(emb + (size_t)z[n] * D + d0);
        *reinterpret_cast<f4*>(x + (size_t)n * D + d0) = v;
        u16x4 h, l;
        #pragma unroll
        for (int c = 0; c < 4; c++) {
            h[c] = f2bf(v[c]);
            l[c] = f2bf(v[c] - bf2f(h[c]));
        }
        *reinterpret_cast<u16x4*>(xh + (size_t)n * D + d0) = h;
        *reinterpret_cast<u16x4*>(xl + (size_t)n * D + d0) = l;
    } else if (b < nb_embed + nb_dist) {
        int e = (b - nb_embed) * 256 + threadIdx.x;
        if (e >= E) return;
        int r = row[e], c = col[e];
        float dx = pos[3 * r + 0] - pos[3 * c + 0];
        float dy = pos[3 * r + 1] - pos[3 * c + 1];
        float dz = pos[3 * r + 2] - pos[3 * c + 2];
        float dist = sqrtf(dx * dx + dy * dy + dz * dz);
        jd[e] = make_int2(r * 256, __float_as_int(dist));   // pre-scaled index
    } else {
        int idx = (b - nb_embed - nb_dist) * 256 + threadIdx.x;
        if (idx >= L * 4 * D * D) return;
        int k = idx & 127;
        int n = (idx >> 7) & 127;
        int mat = (idx >> 14) & 3;
        int l = idx >> 16;
        const float* src = (mat < 2) ? Wf : Ws;
        float scale = (mat < 2) ? -LOG2E : LOG2E;
        float v = scale * src[(size_t)l * 257 * D + (size_t)((mat & 1) * D + k) * D + n];
        unsigned short h = f2bf(v);
        Wth[idx] = h;
        Wtl[idx] = f2bf(v - bf2f(h));
    }
}

// Split-bf16 MFMA GEMM, A-SHARED: each block computes its 128-row tile for a
// PAIR of matrices (y=0: {Af,Bf}, y=1: {As,Bs}), loading Xh/Xl fragments once.
// Outputs interleaved: AfAs[N][256] = [Af|As], BfBs[N][256] = [Bf|Bs]  (pre-scaled)
__global__ __launch_bounds__(256) void k_gemm_mfma(
        const unsigned short* __restrict__ Xh, const unsigned short* __restrict__ Xl,
        const unsigned short* __restrict__ Wth, const unsigned short* __restrict__ Wtl,
        const float* __restrict__ bfl, const float* __restrict__ bsl,
        float* __restrict__ AfAs, float* __restrict__ BfBs, int S, int G) {
    int pair = blockIdx.y;                     // 0: mats {0,1}  1: mats {2,3}
    float* O0 = AfAs + (pair ? 128 : 0);       // mat 2p   (x_i side, has bias)
    float* O1 = BfBs + (pair ? 128 : 0);       // mat 2p+1 (x_j side)
    const float* bias = pair ? bsl : bfl;
    float bsc = pair ? LOG2E : -LOG2E;
    const unsigned short* W0 = Wth + (size_t)(2 * pair) * D * D;
    const unsigned short* W1 = Wth + (size_t)(2 * pair + 1) * D * D;

    int wave = threadIdx.x >> 6;
    int lane = threadIdx.x & 63;
    int r16 = lane & 15;
    int kg = lane >> 4;

    int xb = blockIdx.x;
    int tile0;
    if ((G & 7) == 0 && (S & 127) == 0) {
        int xcd = xb & 7, i = xb >> 3;
        int tpg = S >> 7;                       // 128-row tiles per graph
        int gi = i / tpg, t = i - gi * tpg;
        tile0 = (xcd + 8 * gi) * S + t * 128;   // graph g on XCD g%8
    } else tile0 = xb * 128;
    int row0 = tile0 + (wave >> 1) * 64;
    int wc = (wave & 1) * 64;

    f32x4 acc0[4][4], acc1[4][4];
    #pragma unroll
    for (int m = 0; m < 4; m++)
        #pragma unroll
        for (int n = 0; n < 4; n++) {
            acc0[m][n] = (f32x4){0.f, 0.f, 0.f, 0.f};
            acc1[m][n] = (f32x4){0.f, 0.f, 0.f, 0.f};
        }

    #pragma unroll
    for (int ks = 0; ks < 4; ++ks) {
        int k0 = ks * 32 + kg * 8;
        bf16x8 ah[4], al[4], b0[4], b1[4];
        #pragma unroll
        for (int m = 0; m < 4; m++) {
            size_t off = (size_t)(row0 + m * 16 + r16) * D + k0;
            ah[m] = load_bf8(Xh + off);
            al[m] = load_bf8(Xl + off);
        }
        #pragma unroll
        for (int n = 0; n < 4; n++) {
            size_t off = (size_t)(wc + n * 16 + r16) * D + k0;
            b0[n] = load_bf8(W0 + off);
            b1[n] = load_bf8(W1 + off);
        }
        #pragma unroll
        for (int m = 0; m < 4; m++)
            #pragma unroll
            for (int n = 0; n < 4; n++) {
                acc0[m][n] = __builtin_amdgcn_mfma_f32_16x16x32_bf16(ah[m], b0[n], acc0[m][n], 0, 0, 0);
                acc0[m][n] = __builtin_amdgcn_mfma_f32_16x16x32_bf16(al[m], b0[n], acc0[m][n], 0, 0, 0);
                acc1[m][n] = __builtin_amdgcn_mfma_f32_16x16x32_bf16(ah[m], b1[n], acc1[m][n], 0, 0, 0);
                acc1[m][n] = __builtin_amdgcn_mfma_f32_16x16x32_bf16(al[m], b1[n], acc1[m][n], 0, 0, 0);
            }
    }

    // C/D layout: col = lane&15, row = (lane>>4)*4 + reg
    #pragma unroll
    for (int n = 0; n < 4; n++) {
        int col = wc + n * 16 + r16;
        float bv = bias[col] * bsc;
        #pragma unroll
        for (int m = 0; m < 4; m++) {
            int rbase = row0 + m * 16 + kg * 4;
            #pragma unroll
            for (int r = 0; r < 4; r++) {
                O0[(size_t)(rbase + r) * 256 + col] = acc0[m][n][r] + bv;
                O1[(size_t)(rbase + r) * 256 + col] = acc1[m][n][r];
            }
        }
    }
}

// Edge gate + aggregate + fused 5-way stats (agg, agg^2, x, x^2, agg*x).
// 8 nodes/block, 32 lanes/node, float4/lane; graph-affine XCD swizzle.
// No LDS staging of (j,dist): per-edge jd reads are uniform across the 32-lane
// group (hardware broadcast, L1-hot). Deg loop split into two interleaved
// halves with independent accumulators -> 8 dependency chains per thread.
// st slot layout per block-group (b&7 == XCD under swizzle): 640 floats.
__global__ __launch_bounds__(256) void k_edges(
        const int2* __restrict__ jd,
        const float* __restrict__ AfAs, const float* __restrict__ BfBs,
        const float* __restrict__ wfd, const float* __restrict__ wsd,
        const float* __restrict__ x,
        float* __restrict__ agg, float* __restrict__ st, int N, int S, int G, int deg) {
    __shared__ f4 sred[256];
    __shared__ f4 sredq[256];
    int b = blockIdx.x;
    int node0 = swz_node0(b, S, G);
    int tid = threadIdx.x;
    int grp = tid >> 5, lane = tid & 31;
    int node = node0 + grp;
    bool active = node < N;
    int d0 = lane * 4;
    f4 acc = {0.f, 0.f, 0.f, 0.f};
    f4 xv = {0.f, 0.f, 0.f, 0.f};
    if (active) {
        const f4 af4 = *reinterpret_cast<const f4*>(AfAs + (size_t)node * 256 + d0);
        const f4 as4 = *reinterpret_cast<const f4*>(AfAs + (size_t)node * 256 + 128 + d0);
        const f4 wf4 = *reinterpret_cast<const f4*>(wfd + d0) * (-LOG2E);
        const f4 ws4 = *reinterpret_cast<const f4*>(wsd + d0) * (LOG2E);
        f2v af01 = __builtin_shufflevector(af4, af4, 0, 1);
        f2v af23 = __builtin_shufflevector(af4, af4, 2, 3);
        f2v as01 = __builtin_shufflevector(as4, as4, 0, 1);
        f2v as23 = __builtin_shufflevector(as4, as4, 2, 3);
        f2v wf01 = __builtin_shufflevector(wf4, wf4, 0, 1);
        f2v wf23 = __builtin_shufflevector(wf4, wf4, 2, 3);
        f2v ws01 = __builtin_shufflevector(ws4, ws4, 0, 1);
        f2v ws23 = __builtin_shufflevector(ws4, ws4, 2, 3);
        const int2* jrow = jd + (size_t)node * deg;
        int half = deg >> 1;
        f4 acc2 = {0.f, 0.f, 0.f, 0.f};
        #pragma unroll 4
        for (int e = 0; e < half; e++) {
            int2 p = jrow[e];
            int2 q = jrow[e + half];
            float dp = __int_as_float(p.y);
            float dq = __int_as_float(q.y);
            int offp = p.x + d0;                // p.x pre-scaled by 256
            int offq = q.x + d0;
            f4 bfp = *reinterpret_cast<const f4*>(BfBs + offp);
            f4 bsp = *reinterpret_cast<const f4*>(BfBs + offp + 128);
            f4 bfq = *reinterpret_cast<const f4*>(BfBs + offq);
            f4 bsq = *reinterpret_cast<const f4*>(BfBs + offq + 128);
            // stream 1 (edge e)
            {
                f2v dst2 = {dp, dp};
                f2v u01 = dst2 * wf01 + af01 + __builtin_shufflevector(bfp, bfp, 0, 1);
                f2v u23 = dst2 * wf23 + af23 + __builtin_shufflevector(bfp, bfp, 2, 3);
                f2v v01 = dst2 * ws01 + as01 + __builtin_shufflevector(bsp, bsp, 0, 1);
                f2v v23 = dst2 * ws23 + as23 + __builtin_shufflevector(bsp, bsp, 2, 3);
                float u[4] = {u01[0], u01[1], u23[0], u23[1]};
                float v[4] = {v01[0], v01[1], v23[0], v23[1]};
                #pragma unroll
                for (int c = 0; c < 4; c++) {
                    float sE = exp2_hw(u[c]);                        // e^{-u}
                    float tE = exp2_hw(v[c]);                        // e^{v}
                    float sg = __builtin_amdgcn_rcpf(1.0f + sE);     // sigmoid(u)
                    float sp = log2_hw(1.0f + tE);                   // softplus(v)/ln2
                    acc[c] = fmaf(sg, sp, acc[c]);
                }
            }
            // stream 2 (edge e + deg/2), independent accumulator
            {
                f2v dst2 = {dq, dq};
                f2v u01 = dst2 * wf01 + af01 + __builtin_shufflevector(bfq, bfq, 0, 1);
                f2v u23 = dst2 * wf23 + af23 + __builtin_shufflevector(bfq, bfq, 2, 3);
                f2v v01 = dst2 * ws01 + as01 + __builtin_shufflevector(bsq, bsq, 0, 1);
                f2v v23 = dst2 * ws23 + as23 + __builtin_shufflevector(bsq, bsq, 2, 3);
                float u[4] = {u01[0], u01[1], u23[0], u23[1]};
                float v[4] = {v01[0], v01[1], v23[0], v23[1]};
                #pragma unroll
                for (int c = 0; c < 4; c++) {
                    float sE = exp2_hw(u[c]);
                    float tE = exp2_hw(v[c]);
                    float sg = __builtin_amdgcn_rcpf(1.0f + sE);
                    float sp = log2_hw(1.0f + tE);
                    acc2[c] = fmaf(sg, sp, acc2[c]);
                }
            }
        }
        if (deg & 1) {                          // odd-degree tail
            int2 p = jrow[deg - 1];
            float dp = __int_as_float(p.y);
            int offp = p.x + d0;
            f4 bfp = *reinterpret_cast<const f4*>(BfBs + offp);
            f4 bsp = *reinterpret_cast<const f4*>(BfBs + offp + 128);
            f2v dst2 = {dp, dp};
            f2v u01 = dst2 * wf01 + af01 + __builtin_shufflevector(bfp, bfp, 0, 1);
            f2v u23 = dst2 * wf23 + af23 + __builtin_shufflevector(bfp, bfp, 2, 3);
            f2v v01 = dst2 * ws01 + as01 + __builtin_shufflevector(bsp, bsp, 0, 1);
            f2v v23 = dst2 * ws23 + as23 + __builtin_shufflevector(bsp, bsp, 2, 3);
            float u[4] = {u01[0], u01[1], u23[0], u23[1]};
            float v[4] = {v01[0], v01[1], v23[0], v23[1]};
            #pragma unroll
            for (int c = 0; c < 4; c++) {
                float sE = exp2_hw(u[c]);
                float tE = exp2_hw(v[c]);
                float sg = __builtin_amdgcn_rcpf(1.0f + sE);
                float sp = log2_hw(1.0f + tE);
                acc[c] = fmaf(sg, sp, acc[c]);
            }
        }
        acc += acc2;
        *reinterpret_cast<f4*>(agg + (size_t)node * D + d0) = acc;
        xv = *reinterpret_cast<const f4*>(x + (size_t)node * D + d0);
    }
    float* stb = st + (b & 7) * 640;
    // round 1: sum_agg, sum_agg2
    sred[tid] = acc;
    sredq[tid] = acc * acc;
    __syncthreads();
    if (tid < 64) {
        int which = tid >> 5, l = tid & 31;
        f4 s = which ? sredq[l] : sred[l];
        #pragma unroll
        for (int g = 1; g < 8; g++) s += which ? sredq[g * 32 + l] : sred[g * 32 + l];
        float* dstp = stb + which * 128;
        #pragma unroll
        for (int c = 0; c < 4; c++) atomicAdd(dstp + l * 4 + c, s[c]);
    }
    __syncthreads();
    // round 2: sum_x, sum_x2
    sred[tid] = xv;
    sredq[tid] = xv * xv;
    __syncthreads();
    if (tid < 64) {
        int which = tid >> 5, l = tid & 31;
        f4 s = which ? sredq[l] : sred[l];
        #pragma unroll
        for (int g = 1; g < 8; g++) s += which ? sredq[g * 32 + l] : sred[g * 32 + l];
        float* dstp = stb + 256 + which * 128;
        #pragma unroll
        for (int c = 0; c < 4; c++) atomicAdd(dstp + l * 4 + c, s[c]);
    }
    __syncthreads();
    // round 3: sum_agg*x
    sred[tid] = acc * xv;
    __syncthreads();
    if (tid < 32) {
        f4 s = sred[tid];
        #pragma unroll
        for (int g = 1; g < 8; g++) s += sred[g * 32 + tid];
        #pragma unroll
        for (int c = 0; c < 4; c++) atomicAdd(stb + 512 + tid * 4 + c, s[c]);
    }
}

// Fused BN1+residual+BN2+ReLU, stats2 computed ALGEBRAICALLY:
//   xn = A*agg + C + x,  A = gc*inv1, C = bc - A*mu1
//   mu2 = bc + mean(x)   (A-terms cancel exactly)
//   E[xn^2] = (A^2*Sagg2 + 2AC*Sagg + 2A*Saggx + 2C*Sx + Sx2)/N + C^2
// One pass: read agg + x, write x, xh, xl.  NG blocks, 8 nodes/block, swizzled.
__global__ __launch_bounds__(256) void k_bnfused(
        const float* __restrict__ st,
        const float* __restrict__ gc, const float* __restrict__ bc,
        const float* __restrict__ gn, const float* __restrict__ bnb,
        const float* __restrict__ agg, float* __restrict__ x,
        unsigned short* __restrict__ xh, unsigned short* __restrict__ xl,
        int N, int S, int G) {
    int tid = threadIdx.x;
    int lane = tid & 31, grp = tid >> 5;
    int d0 = lane * 4;
    int node = swz_node0(blockIdx.x, S, G) + grp;
    if (node >= N) return;
    float invN = 1.0f / (float)N;
    f4 Sa = {0.f, 0.f, 0.f, 0.f}, Sa2 = {0.f, 0.f, 0.f, 0.f};
    f4 Sx = {0.f, 0.f, 0.f, 0.f}, Sx2 = {0.f, 0.f, 0.f, 0.f}, Sax = {0.f, 0.f, 0.f, 0.f};
    #pragma unroll
    for (int r = 0; r < 8; r++) {
        const float* stb = st + r * 640;
        Sa  += *reinterpret_cast<const f4*>(stb + d0);
        Sa2 += *reinterpret_cast<const f4*>(stb + 128 + d0);
        Sx  += *reinterpret_cast<const f4*>(stb + 256 + d0);
        Sx2 += *reinterpret_cast<const f4*>(stb + 384 + d0);
        Sax += *reinterpret_cast<const f4*>(stb + 512 + d0);
    }
    f4 g1 = *reinterpret_cast<const f4*>(gc + d0);
    f4 b1v = *reinterpret_cast<const f4*>(bc + d0);
    f4 g2 = *reinterpret_cast<const f4*>(gn + d0);
    f4 b2v = *reinterpret_cast<const f4*>(bnb + d0);
    f4 A, C, mu2, inv2;
    #pragma unroll
    for (int c = 0; c < 4; c++) {
        float m1 = Sa[c] * invN;
        float var1 = Sa2[c] * invN - m1 * m1;
        float i1 = rsqrtf(var1 + 1e-5f);
        float a = g1[c] * i1;
        float cc = b1v[c] - a * m1;
        float mx = Sx[c] * invN;
        float m2 = b1v[c] + mx;
        float e2 = (a * a * Sa2[c] + 2.f * a * cc * Sa[c] + 2.f * a * Sax[c]
                    + 2.f * cc * Sx[c] + Sx2[c]) * invN + cc * cc;
        float var2 = e2 - m2 * m2;
        A[c] = a; C[c] = cc; mu2[c] = m2;
        inv2[c] = rsqrtf(var2 + 1e-5f);
    }
    size_t idx = (size_t)node * D + d0;
    f4 av = *reinterpret_cast<const f4*>(agg + idx);
    f4 xv = *reinterpret_cast<const f4*>(x + idx);
    f4 o;
    u16x4 h, l;
    #pragma unroll
    for (int c = 0; c < 4; c++) {
        float xn = fmaf(A[c], av[c], C[c]) + xv[c];
        float t = fmaf(g2[c] * (xn - mu2[c]), inv2[c], b2v[c]);
        t = fmaxf(t, 0.0f);
        o[c] = t;
        h[c] = f2bf(t);
        l[c] = f2bf(t - bf2f(h[c]));
    }
    *reinterpret_cast<f4*>(x + idx) = o;
    *reinterpret_cast<u16x4*>(xh + idx) = h;
    *reinterpret_cast<u16x4*>(xl + idx) = l;
}

// Per-graph feature sums: 8 blocks per graph (g = b&31 so XCD matches g%8)
__global__ __launch_bounds__(256) void k_pool(const float* __restrict__ x,
        float* __restrict__ gsum, int S, int G) {
    __shared__ f4 s[256];
    int b = blockIdx.x;
    int g, sub;
    if ((G & 31) == 0) { g = b & 31; sub = b >> 5; }
    else               { g = b >> 3; sub = b & 7; }
    int tid = threadIdx.x;
    int grp = tid >> 5, lane = tid & 31;
    int d0 = lane * 4;
    f4 a = {0.f, 0.f, 0.f, 0.f};
    for (int r = sub * 8 + grp; r < S; r += 64)
        a += *reinterpret_cast<const f4*>(x + ((size_t)g * S + r) * D + d0);
    s[tid] = a;
    __syncthreads();
    if (tid < 32) {
        f4 acc = s[tid];
        #pragma unroll
        for (int q = 1; q < 8; q++) acc += s[q * 32 + tid];
        #pragma unroll
        for (int c = 0; c < 4; c++) atomicAdd(&gsum[g * D + tid * 4 + c], acc[c]);
    }
}

// out[g] = relu(gmean@W1+b1) @ W2 + b2
__global__ __launch_bounds__(128) void k_mlp(const float* __restrict__ gsum,
        const float* __restrict__ W1, const float* __restrict__ b1,
        const float* __restrict__ W2, const float* __restrict__ b2,
        float* __restrict__ out, int S) {
    __shared__ float gm[D];
    __shared__ float red[128];
    int g = blockIdx.x, d = threadIdx.x;
    gm[d] = gsum[g * D + d] / (float)S;
    __syncthreads();
    float h = b1[d];
    #pragma unroll 8
    for (int k = 0; k < D; k++) h = fmaf(gm[k], W1[k * D + d], h);
    h = fmaxf(h, 0.0f);
    red[d] = h * W2[d];
    __syncthreads();
    for (int st = 64; st > 0; st >>= 1) {
        if (d < st) red[d] += red[d + st];
        __syncthreads();
    }
    if (d == 0) out[g] = red[0] + b2[0];
}

extern "C" void kernel_launch(void* const* d_in, const int* in_sizes, int n_in,
                              void* d_out, int out_size, void* d_ws, size_t ws_size,
                              hipStream_t stream) {
    const int*   z    = (const int*)d_in[0];
    const float* pos  = (const float*)d_in[1];
    const int*   eidx = (const int*)d_in[3];
    const float* emb  = (const float*)d_in[4];
    const float* Wf   = (const float*)d_in[5];
    const float* bf   = (const float*)d_in[6];
    const float* Ws   = (const float*)d_in[7];
    const float* bs   = (const float*)d_in[8];
    const float* gc   = (const float*)d_in[9];
    const float* bc   = (const float*)d_in[10];
    const float* gn   = (const float*)d_in[11];
    const float* bnb  = (const float*)d_in[12];
    const float* W1   = (const float*)d_in[13];
    const float* b1   = (const float*)d_in[14];
    const float* W2   = (const float*)d_in[15];
    const float* b2   = (const float*)d_in[16];

    int N = in_sizes[0];
    int E = in_sizes[3] / 2;
    int L = in_sizes[6] / D;
    int deg = E / N;
    int G = out_size;
    int S = N / G;

    const int* row = eidx;
    const int* col = eidx + E;

    float* ws = (float*)d_ws;
    size_t nd = (size_t)N * D;
    float* x    = ws;                  // [N][128]
    float* AfAs = x + nd;              // [N][256]
    float* BfBs = AfAs + 2 * nd;       // [N][256]
    float* agg  = BfBs + 2 * nd;       // [N][128]
    int2*  jd   = (int2*)(agg + nd);   // [E] packed (j*256, dist)
    unsigned short* xh  = (unsigned short*)(jd + E);
    unsigned short* xl  = xh + nd;
    unsigned short* Wth = xl + nd;                          // L*4*128*128 bf16
    unsigned short* Wtl = Wth + (size_t)L * 4 * D * D;
    float* stats = (float*)(Wtl + (size_t)L * 4 * D * D);   // L * 8*640 floats
    float* gsum  = stats + (size_t)L * 5120;                // G*128 floats

    hipMemsetAsync(stats, 0, ((size_t)L * 5120 + (size_t)G * D) * sizeof(float), stream);

    int nb_embed = (N * 32 + 255) / 256;
    int nb_dist  = (E + 255) / 256;
    int nb_cvtw  = (L * 4 * D * D + 255) / 256;
    k_setup<<<nb_embed + nb_dist + nb_cvtw, 256, 0, stream>>>(
        z, emb, x, xh, xl, row, col, pos, jd, Wf, Ws, Wth, Wtl,
        N, E, L, nb_embed, nb_dist);

    int NG = (N + 7) / 8;
    for (int l = 0; l < L; ++l) {
        const float* Wfl = Wf + (size_t)l * 257 * D;
        const float* Wsl = Ws + (size_t)l * 257 * D;
        float* stp = stats + (size_t)l * 5120;
        k_gemm_mfma<<<dim3(N / 128, 2), 256, 0, stream>>>(
            xh, xl, Wth + (size_t)l * 4 * D * D, Wtl + (size_t)l * 4 * D * D,
            bf + l * D, bs + l * D, AfAs, BfBs, S, G);
        k_edges<<<NG, 256, 0, stream>>>(jd, AfAs, BfBs, Wfl + 256 * D, Wsl + 256 * D,
                                        x, agg, stp, N, S, G, deg);
        k_bnfused<<<NG, 256, 0, stream>>>(stp, gc + l * D, bc + l * D,
                                          gn + l * D, bnb + l * D,
                                          agg, x, xh, xl, N, S, G);
    }
    k_pool<<<G * 8, 256, 0, stream>>>(x, gsum, S, G);
    k_mlp<<<G, 128, 0, stream>>>(gsum, W1, b1, W2, b2, (float*)d_out, S);
}

// Round 15
// 515.325 us; speedup vs baseline: 3.2059x; 1.0592x over previous
//
#include <hip/hip_runtime.h>
#include <math.h>

#define D 128
#define LOG2E 1.44269504f

typedef short bf16x8 __attribute__((ext_vector_type(8)));
typedef float f32x4 __attribute__((ext_vector_type(4)));
typedef float f4 __attribute__((ext_vector_type(4)));
typedef float f2v __attribute__((ext_vector_type(2)));
typedef unsigned short u16x4 __attribute__((ext_vector_type(4)));

__device__ __forceinline__ unsigned short f2bf(float f) {
    unsigned int u = __float_as_uint(f);
    u += 0x7fff + ((u >> 16) & 1);   // round-to-nearest-even
    return (unsigned short)(u >> 16);
}
__device__ __forceinline__ float bf2f(unsigned short h) {
    return __uint_as_float(((unsigned int)h) << 16);
}
__device__ __forceinline__ bf16x8 load_bf8(const unsigned short* p) {
    return __builtin_bit_cast(bf16x8, *reinterpret_cast<const uint4*>(p));
}
// raw HW transcendentals (v_exp_f32 = 2^x, v_log_f32 = log2)
__device__ __forceinline__ float exp2_hw(float x) {
    float r; asm("v_exp_f32 %0, %1" : "=v"(r) : "v"(x)); return r;
}
__device__ __forceinline__ float log2_hw(float x) {
    float r; asm("v_log_f32 %0, %1" : "=v"(r) : "v"(x)); return r;
}

// graph-affine XCD swizzle: node-group gi -> node0, graph g lands on XCD g%8
__device__ __forceinline__ int swz_node0(int gi, int S, int G) {
    if ((G & 7) == 0 && (S & 7) == 0) {
        int xcd = gi & 7, i = gi >> 3;
        int bpg = S >> 3;
        int gr = i / bpg, li = i - gr * bpg;
        return (xcd + 8 * gr) * S + li * 8;
    }
    return gi * 8;
}

// Merged startup: embed | dist | cvtW, partitioned by blockIdx range.
// jd[e] = (row[e]*256, bits(dist))  -- index pre-scaled for k_edges.
__global__ __launch_bounds__(256) void k_setup(
        const int* __restrict__ z, const float* __restrict__ emb,
        float* __restrict__ x, unsigned short* __restrict__ xh,
        unsigned short* __restrict__ xl,
        const int* __restrict__ row, const int* __restrict__ col,
        const float* __restrict__ pos, int2* __restrict__ jd,
        const float* __restrict__ Wf, const float* __restrict__ Ws,
        unsigned short* __restrict__ Wth, unsigned short* __restrict__ Wtl,
        int N, int E, int L, int nb_embed, int nb_dist) {
    int b = blockIdx.x;
    if (b < nb_embed) {
        int idx = b * 256 + threadIdx.x;                 // N*32 threads
        if (idx >= N * 32) return;
        int n = idx >> 5;
        int d0 = (idx & 31) * 4;
        f4 v = *reinterpret_cast<const f4*>(emb + (size_t)z[n] * D + d0);
        *reinterpret_cast<f4*>(x + (size_t)n * D + d0) = v;
        u16x4 h, l;
        #pragma unroll
        for (int c = 0; c < 4; c++) {
            h[c] = f2bf(v[c]);
            l[c] = f2bf(v[c] - bf2f(h[c]));
        }
        *reinterpret_cast<u16x4*>(xh + (size_t)n * D + d0) = h;
        *reinterpret_cast<u16x4*>(xl + (size_t)n * D + d0) = l;
    } else if (b < nb_embed + nb_dist) {
        int e = (b - nb_embed) * 256 + threadIdx.x;
        if (e >= E) return;
        int r = row[e], c = col[e];
        float dx = pos[3 * r + 0] - pos[3 * c + 0];
        float dy = pos[3 * r + 1] - pos[3 * c + 1];
        float dz = pos[3 * r + 2] - pos[3 * c + 2];
        float dist = sqrtf(dx * dx + dy * dy + dz * dz);
        jd[e] = make_int2(r * 256, __float_as_int(dist));   // pre-scaled index
    } else {
        int idx = (b - nb_embed - nb_dist) * 256 + threadIdx.x;
        if (idx >= L * 4 * D * D) return;
        int k = idx & 127;
        int n = (idx >> 7) & 127;
        int mat = (idx >> 14) & 3;
        int l = idx >> 16;
        const float* src = (mat < 2) ? Wf : Ws;
        float scale = (mat < 2) ? -LOG2E : LOG2E;
        float v = scale * src[(size_t)l * 257 * D + (size_t)((mat & 1) * D + k) * D + n];
        unsigned short h = f2bf(v);
        Wth[idx] = h;
        Wtl[idx] = f2bf(v - bf2f(h));
    }
}

// Split-bf16 MFMA GEMM, A-SHARED: each block computes its 128-row tile for a
// PAIR of matrices (y=0: {Af,Bf}, y=1: {As,Bs}), loading Xh/Xl fragments once.
// Outputs interleaved: AfAs[N][256] = [Af|As], BfBs[N][256] = [Bf|Bs]  (pre-scaled)
__global__ __launch_bounds__(256) void k_gemm_mfma(
        const unsigned short* __restrict__ Xh, const unsigned short* __restrict__ Xl,
        const unsigned short* __restrict__ Wth, const unsigned short* __restrict__ Wtl,
        const float* __restrict__ bfl, const float* __restrict__ bsl,
        float* __restrict__ AfAs, float* __restrict__ BfBs, int S, int G) {
    int pair = blockIdx.y;                     // 0: mats {0,1}  1: mats {2,3}
    float* O0 = AfAs + (pair ? 128 : 0);       // mat 2p   (x_i side, has bias)
    float* O1 = BfBs + (pair ? 128 : 0);       // mat 2p+1 (x_j side)
    const float* bias = pair ? bsl : bfl;
    float bsc = pair ? LOG2E : -LOG2E;
    const unsigned short* W0 = Wth + (size_t)(2 * pair) * D * D;
    const unsigned short* W1 = Wth + (size_t)(2 * pair + 1) * D * D;

    int wave = threadIdx.x >> 6;
    int lane = threadIdx.x & 63;
    int r16 = lane & 15;
    int kg = lane >> 4;

    int xb = blockIdx.x;
    int tile0;
    if ((G & 7) == 0 && (S & 127) == 0) {
        int xcd = xb & 7, i = xb >> 3;
        int tpg = S >> 7;                       // 128-row tiles per graph
        int gi = i / tpg, t = i - gi * tpg;
        tile0 = (xcd + 8 * gi) * S + t * 128;   // graph g on XCD g%8
    } else tile0 = xb * 128;
    int row0 = tile0 + (wave >> 1) * 64;
    int wc = (wave & 1) * 64;

    f32x4 acc0[4][4], acc1[4][4];
    #pragma unroll
    for (int m = 0; m < 4; m++)
        #pragma unroll
        for (int n = 0; n < 4; n++) {
            acc0[m][n] = (f32x4){0.f, 0.f, 0.f, 0.f};
            acc1[m][n] = (f32x4){0.f, 0.f, 0.f, 0.f};
        }

    #pragma unroll
    for (int ks = 0; ks < 4; ++ks) {
        int k0 = ks * 32 + kg * 8;
        bf16x8 ah[4], al[4], b0[4], b1[4];
        #pragma unroll
        for (int m = 0; m < 4; m++) {
            size_t off = (size_t)(row0 + m * 16 + r16) * D + k0;
            ah[m] = load_bf8(Xh + off);
            al[m] = load_bf8(Xl + off);
        }
        #pragma unroll
        for (int n = 0; n < 4; n++) {
            size_t off = (size_t)(wc + n * 16 + r16) * D + k0;
            b0[n] = load_bf8(W0 + off);
            b1[n] = load_bf8(W1 + off);
        }
        #pragma unroll
        for (int m = 0; m < 4; m++)
            #pragma unroll
            for (int n = 0; n < 4; n++) {
                acc0[m][n] = __builtin_amdgcn_mfma_f32_16x16x32_bf16(ah[m], b0[n], acc0[m][n], 0, 0, 0);
                acc0[m][n] = __builtin_amdgcn_mfma_f32_16x16x32_bf16(al[m], b0[n], acc0[m][n], 0, 0, 0);
                acc1[m][n] = __builtin_amdgcn_mfma_f32_16x16x32_bf16(ah[m], b1[n], acc1[m][n], 0, 0, 0);
                acc1[m][n] = __builtin_amdgcn_mfma_f32_16x16x32_bf16(al[m], b1[n], acc1[m][n], 0, 0, 0);
            }
    }

    // C/D layout: col = lane&15, row = (lane>>4)*4 + reg
    #pragma unroll
    for (int n = 0; n < 4; n++) {
        int col = wc + n * 16 + r16;
        float bv = bias[col] * bsc;
        #pragma unroll
        for (int m = 0; m < 4; m++) {
            int rbase = row0 + m * 16 + kg * 4;
            #pragma unroll
            for (int r = 0; r < 4; r++) {
                O0[(size_t)(rbase + r) * 256 + col] = acc0[m][n][r] + bv;
                O1[(size_t)(rbase + r) * 256 + col] = acc1[m][n][r];
            }
        }
    }
}

// Edge gate + aggregate + fused 5-way stats (agg, agg^2, x, x^2, agg*x).
// 8 nodes/block, 32 lanes/node, float4/lane; graph-affine XCD swizzle.
// st slot layout per block-group (b&7 == XCD under swizzle): 640 floats.
__global__ __launch_bounds__(256) void k_edges(
        const int2* __restrict__ jd,
        const float* __restrict__ AfAs, const float* __restrict__ BfBs,
        const float* __restrict__ wfd, const float* __restrict__ wsd,
        const float* __restrict__ x,
        float* __restrict__ agg, float* __restrict__ st, int N, int S, int G, int deg) {
    __shared__ f4 sred[256];
    __shared__ f4 sredq[256];
    int b = blockIdx.x;
    int node0 = swz_node0(b, S, G);
    int tid = threadIdx.x;
    int grp = tid >> 5, lane = tid & 31;
    int node = node0 + grp;
    bool active = node < N;
    int d0 = lane * 4;
    f4 acc = {0.f, 0.f, 0.f, 0.f};
    f4 xv = {0.f, 0.f, 0.f, 0.f};
    if (active) {
        const f4 af4 = *reinterpret_cast<const f4*>(AfAs + (size_t)node * 256 + d0);
        const f4 as4 = *reinterpret_cast<const f4*>(AfAs + (size_t)node * 256 + 128 + d0);
        const f4 wf4 = *reinterpret_cast<const f4*>(wfd + d0) * (-LOG2E);
        const f4 ws4 = *reinterpret_cast<const f4*>(wsd + d0) * (LOG2E);
        f2v af01 = __builtin_shufflevector(af4, af4, 0, 1);
        f2v af23 = __builtin_shufflevector(af4, af4, 2, 3);
        f2v as01 = __builtin_shufflevector(as4, as4, 0, 1);
        f2v as23 = __builtin_shufflevector(as4, as4, 2, 3);
        f2v wf01 = __builtin_shufflevector(wf4, wf4, 0, 1);
        f2v wf23 = __builtin_shufflevector(wf4, wf4, 2, 3);
        f2v ws01 = __builtin_shufflevector(ws4, ws4, 0, 1);
        f2v ws23 = __builtin_shufflevector(ws4, ws4, 2, 3);
        const int2* jrow = jd + (size_t)node * deg;
        int half = deg >> 1;
        f4 acc2 = {0.f, 0.f, 0.f, 0.f};
        #pragma unroll 4
        for (int e = 0; e < half; e++) {
            int2 p = jrow[e];
            int2 q = jrow[e + half];
            float dp = __int_as_float(p.y);
            float dq = __int_as_float(q.y);
            int offp = p.x + d0;                // p.x pre-scaled by 256
            int offq = q.x + d0;
            f4 bfp = *reinterpret_cast<const f4*>(BfBs + offp);
            f4 bsp = *reinterpret_cast<const f4*>(BfBs + offp + 128);
            f4 bfq = *reinterpret_cast<const f4*>(BfBs + offq);
            f4 bsq = *reinterpret_cast<const f4*>(BfBs + offq + 128);
            {
                f2v dst2 = {dp, dp};
                f2v u01 = dst2 * wf01 + af01 + __builtin_shufflevector(bfp, bfp, 0, 1);
                f2v u23 = dst2 * wf23 + af23 + __builtin_shufflevector(bfp, bfp, 2, 3);
                f2v v01 = dst2 * ws01 + as01 + __builtin_shufflevector(bsp, bsp, 0, 1);
                f2v v23 = dst2 * ws23 + as23 + __builtin_shufflevector(bsp, bsp, 2, 3);
                float u[4] = {u01[0], u01[1], u23[0], u23[1]};
                float v[4] = {v01[0], v01[1], v23[0], v23[1]};
                #pragma unroll
                for (int c = 0; c < 4; c++) {
                    float sE = exp2_hw(u[c]);
                    float tE = exp2_hw(v[c]);
                    float sg = __builtin_amdgcn_rcpf(1.0f + sE);
                    float sp = log2_hw(1.0f + tE);
                    acc[c] = fmaf(sg, sp, acc[c]);
                }
            }
            {
                f2v dst2 = {dq, dq};
                f2v u01 = dst2 * wf01 + af01 + __builtin_shufflevector(bfq, bfq, 0, 1);
                f2v u23 = dst2 * wf23 + af23 + __builtin_shufflevector(bfq, bfq, 2, 3);
                f2v v01 = dst2 * ws01 + as01 + __builtin_shufflevector(bsq, bsq, 0, 1);
                f2v v23 = dst2 * ws23 + as23 + __builtin_shufflevector(bsq, bsq, 2, 3);
                float u[4] = {u01[0], u01[1], u23[0], u23[1]};
                float v[4] = {v01[0], v01[1], v23[0], v23[1]};
                #pragma unroll
                for (int c = 0; c < 4; c++) {
                    float sE = exp2_hw(u[c]);
                    float tE = exp2_hw(v[c]);
                    float sg = __builtin_amdgcn_rcpf(1.0f + sE);
                    float sp = log2_hw(1.0f + tE);
                    acc2[c] = fmaf(sg, sp, acc2[c]);
                }
            }
        }
        if (deg & 1) {
            int2 p = jrow[deg - 1];
            float dp = __int_as_float(p.y);
            int offp = p.x + d0;
            f4 bfp = *reinterpret_cast<const f4*>(BfBs + offp);
            f4 bsp = *reinterpret_cast<const f4*>(BfBs + offp + 128);
            f2v dst2 = {dp, dp};
            f2v u01 = dst2 * wf01 + af01 + __builtin_shufflevector(bfp, bfp, 0, 1);
            f2v u23 = dst2 * wf23 + af23 + __builtin_shufflevector(bfp, bfp, 2, 3);
            f2v v01 = dst2 * ws01 + as01 + __builtin_shufflevector(bsp, bsp, 0, 1);
            f2v v23 = dst2 * ws23 + as23 + __builtin_shufflevector(bsp, bsp, 2, 3);
            float u[4] = {u01[0], u01[1], u23[0], u23[1]};
            float v[4] = {v01[0], v01[1], v23[0], v23[1]};
            #pragma unroll
            for (int c = 0; c < 4; c++) {
                float sE = exp2_hw(u[c]);
                float tE = exp2_hw(v[c]);
                float sg = __builtin_amdgcn_rcpf(1.0f + sE);
                float sp = log2_hw(1.0f + tE);
                acc[c] = fmaf(sg, sp, acc[c]);
            }
        }
        acc += acc2;
        *reinterpret_cast<f4*>(agg + (size_t)node * D + d0) = acc;
        xv = *reinterpret_cast<const f4*>(x + (size_t)node * D + d0);
    }
    float* stb = st + (b & 7) * 640;
    // round 1: sum_agg, sum_agg2
    sred[tid] = acc;
    sredq[tid] = acc * acc;
    __syncthreads();
    if (tid < 64) {
        int which = tid >> 5, l = tid & 31;
        f4 s = which ? sredq[l] : sred[l];
        #pragma unroll
        for (int g = 1; g < 8; g++) s += which ? sredq[g * 32 + l] : sred[g * 32 + l];
        float* dstp = stb + which * 128;
        #pragma unroll
        for (int c = 0; c < 4; c++) atomicAdd(dstp + l * 4 + c, s[c]);
    }
    __syncthreads();
    // round 2: sum_x, sum_x2
    sred[tid] = xv;
    sredq[tid] = xv * xv;
    __syncthreads();
    if (tid < 64) {
        int which = tid >> 5, l = tid & 31;
        f4 s = which ? sredq[l] : sred[l];
        #pragma unroll
        for (int g = 1; g < 8; g++) s += which ? sredq[g * 32 + l] : sred[g * 32 + l];
        float* dstp = stb + 256 + which * 128;
        #pragma unroll
        for (int c = 0; c < 4; c++) atomicAdd(dstp + l * 4 + c, s[c]);
    }
    __syncthreads();
    // round 3: sum_agg*x
    sred[tid] = acc * xv;
    __syncthreads();
    if (tid < 32) {
        f4 s = sred[tid];
        #pragma unroll
        for (int g = 1; g < 8; g++) s += sred[g * 32 + tid];
        #pragma unroll
        for (int c = 0; c < 4; c++) atomicAdd(stb + 512 + tid * 4 + c, s[c]);
    }
}

// Fused BN1+residual+BN2+ReLU; BN constants computed ONCE PER BLOCK (threads
// 0-127, one channel each) into LDS, then the streaming phase reads LDS.
// If gsum != nullptr (last layer): pool o into gsum[g] and SKIP x/xh/xl writes.
__global__ __launch_bounds__(256) void k_bnfused(
        const float* __restrict__ st,
        const float* __restrict__ gc, const float* __restrict__ bc,
        const float* __restrict__ gn, const float* __restrict__ bnb,
        const float* __restrict__ agg, float* __restrict__ x,
        unsigned short* __restrict__ xh, unsigned short* __restrict__ xl,
        float* __restrict__ gsum, int N, int S, int G) {
    __shared__ float sA[128], sC[128], sMu[128], sInv[128];
    __shared__ f4 sred[256];
    int tid = threadIdx.x;
    int lane = tid & 31, grp = tid >> 5;
    int d0 = lane * 4;
    int node0 = swz_node0(blockIdx.x, S, G);
    int node = node0 + grp;
    float invN = 1.0f / (float)N;
    if (tid < 128) {
        int ch = tid;
        float Sa = 0.f, Sa2 = 0.f, Sx = 0.f, Sx2 = 0.f, Sax = 0.f;
        #pragma unroll
        for (int r = 0; r < 8; r++) {
            const float* stb = st + r * 640;
            Sa  += stb[ch];
            Sa2 += stb[128 + ch];
            Sx  += stb[256 + ch];
            Sx2 += stb[384 + ch];
            Sax += stb[512 + ch];
        }
        float m1 = Sa * invN;
        float var1 = Sa2 * invN - m1 * m1;
        float i1 = rsqrtf(var1 + 1e-5f);
        float a = gc[ch] * i1;
        float cc = bc[ch] - a * m1;
        float mx = Sx * invN;
        float m2 = bc[ch] + mx;
        float e2 = (a * a * Sa2 + 2.f * a * cc * Sa + 2.f * a * Sax
                    + 2.f * cc * Sx + Sx2) * invN + cc * cc;
        float var2 = e2 - m2 * m2;
        sA[ch] = a;
        sC[ch] = cc;
        sMu[ch] = m2;
        sInv[ch] = gn[ch] * rsqrtf(var2 + 1e-5f);   // fold gn into inv2
    }
    __syncthreads();
    f4 o = {0.f, 0.f, 0.f, 0.f};
    if (node < N) {
        f4 A   = *reinterpret_cast<const f4*>(sA + d0);
        f4 C   = *reinterpret_cast<const f4*>(sC + d0);
        f4 mu2 = *reinterpret_cast<const f4*>(sMu + d0);
        f4 gi2 = *reinterpret_cast<const f4*>(sInv + d0);
        f4 b2v = *reinterpret_cast<const f4*>(bnb + d0);
        size_t idx = (size_t)node * D + d0;
        f4 av = *reinterpret_cast<const f4*>(agg + idx);
        f4 xv = *reinterpret_cast<const f4*>(x + idx);
        #pragma unroll
        for (int c = 0; c < 4; c++) {
            float xn = fmaf(A[c], av[c], C[c]) + xv[c];
            float t = fmaf((xn - mu2[c]), gi2[c], b2v[c]);
            o[c] = fmaxf(t, 0.0f);
        }
        if (!gsum) {
            u16x4 h, l;
            #pragma unroll
            for (int c = 0; c < 4; c++) {
                h[c] = f2bf(o[c]);
                l[c] = f2bf(o[c] - bf2f(h[c]));
            }
            *reinterpret_cast<f4*>(x + idx) = o;
            *reinterpret_cast<u16x4*>(xh + idx) = h;
            *reinterpret_cast<u16x4*>(xl + idx) = l;
        }
    }
    if (gsum) {
        // pool: all 8 nodes of this block belong to graph node0/S
        sred[tid] = o;
        __syncthreads();
        if (tid < 32) {
            f4 s = sred[tid];
            #pragma unroll
            for (int q = 1; q < 8; q++) s += sred[q * 32 + tid];
            int g = node0 / S;
            #pragma unroll
            for (int c = 0; c < 4; c++) atomicAdd(&gsum[g * D + tid * 4 + c], s[c]);
        }
    }
}

// out[g] = relu(gmean@W1+b1) @ W2 + b2
__global__ __launch_bounds__(128) void k_mlp(const float* __restrict__ gsum,
        const float* __restrict__ W1, const float* __restrict__ b1,
        const float* __restrict__ W2, const float* __restrict__ b2,
        float* __restrict__ out, int S) {
    __shared__ float gm[D];
    __shared__ float red[128];
    int g = blockIdx.x, d = threadIdx.x;
    gm[d] = gsum[g * D + d] / (float)S;
    __syncthreads();
    float h = b1[d];
    #pragma unroll 8
    for (int k = 0; k < D; k++) h = fmaf(gm[k], W1[k * D + d], h);
    h = fmaxf(h, 0.0f);
    red[d] = h * W2[d];
    __syncthreads();
    for (int st = 64; st > 0; st >>= 1) {
        if (d < st) red[d] += red[d + st];
        __syncthreads();
    }
    if (d == 0) out[g] = red[0] + b2[0];
}

extern "C" void kernel_launch(void* const* d_in, const int* in_sizes, int n_in,
                              void* d_out, int out_size, void* d_ws, size_t ws_size,
                              hipStream_t stream) {
    const int*   z    = (const int*)d_in[0];
    const float* pos  = (const float*)d_in[1];
    const int*   eidx = (const int*)d_in[3];
    const float* emb  = (const float*)d_in[4];
    const float* Wf   = (const float*)d_in[5];
    const float* bf   = (const float*)d_in[6];
    const float* Ws   = (const float*)d_in[7];
    const float* bs   = (const float*)d_in[8];
    const float* gc   = (const float*)d_in[9];
    const float* bc   = (const float*)d_in[10];
    const float* gn   = (const float*)d_in[11];
    const float* bnb  = (const float*)d_in[12];
    const float* W1   = (const float*)d_in[13];
    const float* b1   = (const float*)d_in[14];
    const float* W2   = (const float*)d_in[15];
    const float* b2   = (const float*)d_in[16];

    int N = in_sizes[0];
    int E = in_sizes[3] / 2;
    int L = in_sizes[6] / D;
    int deg = E / N;
    int G = out_size;
    int S = N / G;

    const int* row = eidx;
    const int* col = eidx + E;

    float* ws = (float*)d_ws;
    size_t nd = (size_t)N * D;
    float* x    = ws;                  // [N][128]
    float* AfAs = x + nd;              // [N][256]
    float* BfBs = AfAs + 2 * nd;       // [N][256]
    float* agg  = BfBs + 2 * nd;       // [N][128]
    int2*  jd   = (int2*)(agg + nd);   // [E] packed (j*256, dist)
    unsigned short* xh  = (unsigned short*)(jd + E);
    unsigned short* xl  = xh + nd;
    unsigned short* Wth = xl + nd;                          // L*4*128*128 bf16
    unsigned short* Wtl = Wth + (size_t)L * 4 * D * D;
    float* stats = (float*)(Wtl + (size_t)L * 4 * D * D);   // L * 8*640 floats
    float* gsum  = stats + (size_t)L * 5120;                // G*128 floats

    hipMemsetAsync(stats, 0, ((size_t)L * 5120 + (size_t)G * D) * sizeof(float), stream);

    int nb_embed = (N * 32 + 255) / 256;
    int nb_dist  = (E + 255) / 256;
    int nb_cvtw  = (L * 4 * D * D + 255) / 256;
    k_setup<<<nb_embed + nb_dist + nb_cvtw, 256, 0, stream>>>(
        z, emb, x, xh, xl, row, col, pos, jd, Wf, Ws, Wth, Wtl,
        N, E, L, nb_embed, nb_dist);

    int NG = (N + 7) / 8;
    for (int l = 0; l < L; ++l) {
        const float* Wfl = Wf + (size_t)l * 257 * D;
        const float* Wsl = Ws + (size_t)l * 257 * D;
        float* stp = stats + (size_t)l * 5120;
        k_gemm_mfma<<<dim3(N / 128, 2), 256, 0, stream>>>(
            xh, xl, Wth + (size_t)l * 4 * D * D, Wtl + (size_t)l * 4 * D * D,
            bf + l * D, bs + l * D, AfAs, BfBs, S, G);
        k_edges<<<NG, 256, 0, stream>>>(jd, AfAs, BfBs, Wfl + 256 * D, Wsl + 256 * D,
                                        x, agg, stp, N, S, G, deg);
        k_bnfused<<<NG, 256, 0, stream>>>(stp, gc + l * D, bc + l * D,
                                          gn + l * D, bnb + l * D,
                                          agg, x, xh, xl,
                                          (l == L - 1) ? gsum : nullptr, N, S, G);
    }
    k_mlp<<<G, 128, 0, stream>>>(gsum, W1, b1, W2, b2, (float*)d_out, S);
}